// Round 5
// baseline (4358.467 us; speedup 1.0000x reference)
//
#include <hip/hip_runtime.h>
#include <stdint.h>
#include <math.h>

typedef __attribute__((ext_vector_type(8))) short short8;
typedef __attribute__((ext_vector_type(4))) short short4v;
typedef __attribute__((ext_vector_type(4))) float f32x4;

#define NBLK 256

__device__ __forceinline__ short f2bf(float f){
  union { float f; uint32_t u; } x; x.f = f;
  uint32_t r = x.u + 0x7fffu + ((x.u >> 16) & 1u);
  return (short)(r >> 16);
}
__device__ __forceinline__ float bf2f(short s){
  union { uint32_t u; float f; } x; x.u = ((uint32_t)(uint16_t)s) << 16;
  return x.f;
}

// grid barrier: monotonic counter, agent scope (proven correct in R4 run).
__device__ __forceinline__ void gbar(unsigned* cnt, unsigned target){
  __syncthreads();
  if (threadIdx.x == 0){
    __threadfence();
    __hip_atomic_fetch_add(cnt, 1u, __ATOMIC_RELAXED, __HIP_MEMORY_SCOPE_AGENT);
    while (__hip_atomic_load(cnt, __ATOMIC_RELAXED, __HIP_MEMORY_SCOPE_AGENT) < target)
      __builtin_amdgcn_s_sleep(2);
    __threadfence();
  }
  __syncthreads();
}

// ---------------- prep kernels ----------------

// Transposed, bf16, concatenated weights: W3T[j][k], j in [0,4096), k in [0,3072)
__global__ __launch_bounds__(256) void k_wt(const float* __restrict__ Wx,
                                            const float* __restrict__ Wh,
                                            const float* __restrict__ Wattn,
                                            short* __restrict__ W3T){
  __shared__ float tile[64][65];
  int bk = blockIdx.x % 48, bj = blockIdx.x / 48;
  int tx = threadIdx.x & 63, ty = threadIdx.x >> 6;
  int k0 = bk * 64, j0 = bj * 64;
  #pragma unroll
  for (int i = 0; i < 16; ++i){
    int kk = ty * 16 + i;
    int k = k0 + kk;
    const float* src = (k < 1024) ? (Wx + (size_t)k * 4096)
                     : (k < 2048) ? (Wh + (size_t)(k - 1024) * 4096)
                                  : (Wattn + (size_t)(k - 2048) * 4096);
    tile[kk][tx] = src[j0 + tx];
  }
  __syncthreads();
  #pragma unroll
  for (int i = 0; i < 16; ++i){
    int jj = ty * 16 + i;
    W3T[(size_t)(j0 + jj) * 3072 + k0 + tx] = f2bf(tile[tx][jj]);
  }
}

__global__ __launch_bounds__(256) void k_cast(const float* __restrict__ in,
                                              short* __restrict__ out, int n4){
  int i = blockIdx.x * 256 + threadIdx.x;
  if (i >= n4) return;
  float4 v = ((const float4*)in)[i];
  short4v o; o[0] = f2bf(v.x); o[1] = f2bf(v.y); o[2] = f2bf(v.z); o[3] = f2bf(v.w);
  *(short4v*)(out + (size_t)i * 4) = o;
}

// h0 = c0 = mean over L=16 of A; also zero the barrier counter
__global__ __launch_bounds__(256) void k_init(const float* __restrict__ A,
                                              float* __restrict__ c,
                                              short* __restrict__ hb0,
                                              unsigned* __restrict__ barcnt){
  int idx = blockIdx.x * 256 + threadIdx.x;    // N*H = 131072
  if (idx == 0) *barcnt = 0u;
  const float* p = A + (size_t)idx * 16;
  float s = 0.f;
  #pragma unroll
  for (int l = 0; l < 16; ++l) s += p[l];
  s *= (1.f / 16.f);
  c[idx] = s;
  hb0[idx] = f2bf(s);
}

// ---------------- persistent recurrence kernel ----------------
// 256 blocks x 512 threads, 1 block/CU (launch_bounds(512,1) -> 256 VGPR).
// Block tile: 32 n x 16 u x 4 gates (64 j-cols). 8 waves K-split (384 each),
// chunk=64 double-buffered streaming of A and W from L2. LDS reduce.
// c lives in epilogue-wave registers for all 64 steps.
__global__ __launch_bounds__(512, 1) void k_loop(
    const short* __restrict__ W3T,
    const short* __restrict__ xbf,     // [128][64][1024] bf16
    const short* __restrict__ Abf,     // [128][1024][16] bf16
    short* __restrict__ hbuf,          // [2][128][1024] bf16
    short* __restrict__ abuf,          // [128][1024] bf16
    const float* __restrict__ cbuf,    // [128][1024] f32
    const float* __restrict__ bias,    // [4096]
    float* __restrict__ out,           // [128][64][1024] f32
    unsigned* __restrict__ barcnt)
{
  const int tid  = threadIdx.x;
  const int lane = tid & 63;
  const int wave = tid >> 6;           // 0..7 = K-chunk owner
  const int bid  = blockIdx.x;         // 0..255
  const int xcd  = bid & 7;
  const int idx  = bid >> 3;           // 0..31
  const int m0   = (idx & 3) * 32;
  const int u0   = (xcd * 8 + (idx >> 2)) * 16;
  const int ra   = lane & 15;
  const int q    = lane >> 4;
  const int kw0  = wave * 384;

  __shared__ float red[8][2][4][64][4];   // 64 KB
  __shared__ float sred[8][16];

  // persistent per-thread LSTM state (epilogue waves only)
  const int u = u0 + ra;
  float creg[4];
  float bi = 0.f, bf_ = 0.f, bo = 0.f, bg = 0.f;
  if (wave < 2){
    #pragma unroll
    for (int i = 0; i < 4; ++i){
      int n = m0 + wave * 16 + q * 4 + i;
      creg[i] = cbuf[(size_t)n * 1024 + u];
    }
    bi = bias[u]; bf_ = bias[1024 + u]; bo = bias[2048 + u]; bg = bias[3072 + u];
  }

  unsigned phase = 0;

  for (int t = 0; t < 64; ++t){
    const short* hR = hbuf + (size_t)(t & 1) * 131072;
    short*       hW = hbuf + (size_t)((t + 1) & 1) * 131072;

    // ---------- phase A: attention (blocks 0..127, one per n) ----------
    short8 a00, a01, a10, a11; float h0v = 0.f, h1v = 0.f;
    if (bid < 128){
      const int n = bid;
      h0v = bf2f(hR[n * 1024 + tid * 2 + 0]);
      h1v = bf2f(hR[n * 1024 + tid * 2 + 1]);
      const short8* ap0 = (const short8*)(Abf + ((size_t)n * 1024 + tid * 2 + 0) * 16);
      const short8* ap1 = (const short8*)(Abf + ((size_t)n * 1024 + tid * 2 + 1) * 16);
      a00 = ap0[0]; a01 = ap0[1]; a10 = ap1[0]; a11 = ap1[1];
      float sc[16];
      #pragma unroll
      for (int l = 0; l < 8; ++l){
        sc[l]     = h0v * bf2f(a00[l]) + h1v * bf2f(a10[l]);
        sc[8 + l] = h0v * bf2f(a01[l]) + h1v * bf2f(a11[l]);
      }
      #pragma unroll
      for (int off = 1; off < 64; off <<= 1)
        #pragma unroll
        for (int l = 0; l < 16; ++l) sc[l] += __shfl_xor(sc[l], off);
      if (lane == 0)
        #pragma unroll
        for (int l = 0; l < 16; ++l) sred[wave][l] = sc[l];
    }
    __syncthreads();
    if (bid < 128){
      const int n = bid;
      float s[16], mx = -1e30f, sum = 0.f;
      #pragma unroll
      for (int l = 0; l < 16; ++l){
        float v = sred[0][l];
        #pragma unroll
        for (int w = 1; w < 8; ++w) v += sred[w][l];
        s[l] = v * 0.03125f;
        mx = fmaxf(mx, s[l]);
      }
      #pragma unroll
      for (int l = 0; l < 16; ++l){ s[l] = __expf(s[l] - mx); sum += s[l]; }
      const float inv = 1.f / sum;
      float ac0 = 0.f, ac1 = 0.f;
      #pragma unroll
      for (int l = 0; l < 8; ++l){
        ac0 += s[l] * bf2f(a00[l]) + s[8 + l] * bf2f(a01[l]);
        ac1 += s[l] * bf2f(a10[l]) + s[8 + l] * bf2f(a11[l]);
      }
      abuf[n * 1024 + tid * 2 + 0] = f2bf(ac0 * inv);
      abuf[n * 1024 + tid * 2 + 1] = f2bf(ac1 * inv);
    }
    gbar(barcnt, ++phase * NBLK);     // barA: attn visible everywhere

    // ---------- phase B: GEMM (wave's 384-K window, 6 chunks of 64) ----------
    f32x4 acc[2][4];
    #pragma unroll
    for (int mf = 0; mf < 2; ++mf)
      #pragma unroll
      for (int g = 0; g < 4; ++g) acc[mf][g] = f32x4{0.f,0.f,0.f,0.f};

    auto loadA = [&](int c, int mf, int i) -> short8 {
      const int k = kw0 + c * 64 + i * 32 + q * 8;
      const int row = m0 + mf * 16 + ra;
      const short* p = (k < 1024) ? (xbf + (size_t)row * 65536 + t * 1024 + k)
                     : (k < 2048) ? (hR + (size_t)row * 1024 + (k - 1024))
                                  : (abuf + (size_t)row * 1024 + (k - 2048));
      return *(const short8*)p;
    };
    auto loadB = [&](int c, int g, int i) -> short8 {
      const int k = kw0 + c * 64 + i * 32 + q * 8;
      return *(const short8*)(W3T + (size_t)(g * 1024 + u0 + ra) * 3072 + k);
    };

    short8 Ab0[2][2], Bb0[4][2], Ab1[2][2], Bb1[4][2];
    // prologue: chunk0 -> buf0, chunk1 -> buf1
    #pragma unroll
    for (int mf = 0; mf < 2; ++mf){ Ab0[mf][0] = loadA(0, mf, 0); Ab0[mf][1] = loadA(0, mf, 1); }
    #pragma unroll
    for (int g = 0; g < 4; ++g){ Bb0[g][0] = loadB(0, g, 0); Bb0[g][1] = loadB(0, g, 1); }
    #pragma unroll
    for (int mf = 0; mf < 2; ++mf){ Ab1[mf][0] = loadA(1, mf, 0); Ab1[mf][1] = loadA(1, mf, 1); }
    #pragma unroll
    for (int g = 0; g < 4; ++g){ Bb1[g][0] = loadB(1, g, 0); Bb1[g][1] = loadB(1, g, 1); }

    #pragma unroll
    for (int c = 0; c < 6; ++c){
      if ((c & 1) == 0){
        #pragma unroll
        for (int i = 0; i < 2; ++i)
          #pragma unroll
          for (int mf = 0; mf < 2; ++mf)
            #pragma unroll
            for (int g = 0; g < 4; ++g)
              acc[mf][g] = __builtin_amdgcn_mfma_f32_16x16x32_bf16(Ab0[mf][i], Bb0[g][i], acc[mf][g], 0, 0, 0);
        if (c + 2 < 6){
          #pragma unroll
          for (int mf = 0; mf < 2; ++mf){ Ab0[mf][0] = loadA(c + 2, mf, 0); Ab0[mf][1] = loadA(c + 2, mf, 1); }
          #pragma unroll
          for (int g = 0; g < 4; ++g){ Bb0[g][0] = loadB(c + 2, g, 0); Bb0[g][1] = loadB(c + 2, g, 1); }
        }
      } else {
        #pragma unroll
        for (int i = 0; i < 2; ++i)
          #pragma unroll
          for (int mf = 0; mf < 2; ++mf)
            #pragma unroll
            for (int g = 0; g < 4; ++g)
              acc[mf][g] = __builtin_amdgcn_mfma_f32_16x16x32_bf16(Ab1[mf][i], Bb1[g][i], acc[mf][g], 0, 0, 0);
        if (c + 2 < 6){
          #pragma unroll
          for (int mf = 0; mf < 2; ++mf){ Ab1[mf][0] = loadA(c + 2, mf, 0); Ab1[mf][1] = loadA(c + 2, mf, 1); }
          #pragma unroll
          for (int g = 0; g < 4; ++g){ Bb1[g][0] = loadB(c + 2, g, 0); Bb1[g][1] = loadB(c + 2, g, 1); }
        }
      }
    }

    // cross-wave reduction
    #pragma unroll
    for (int mf = 0; mf < 2; ++mf)
      #pragma unroll
      for (int g = 0; g < 4; ++g)
        *(f32x4*)&red[wave][mf][g][lane][0] = acc[mf][g];
    __syncthreads();

    if (wave < 2){
      const int mf = wave;
      f32x4 tot[4];
      #pragma unroll
      for (int g = 0; g < 4; ++g){
        f32x4 s = *(const f32x4*)&red[0][mf][g][lane][0];
        #pragma unroll
        for (int w = 1; w < 8; ++w) s += *(const f32x4*)&red[w][mf][g][lane][0];
        tot[g] = s;
      }
      #pragma unroll
      for (int i = 0; i < 4; ++i){
        const int n = m0 + mf * 16 + q * 4 + i;
        const float av = tot[0][i] + bi;
        const float fv = tot[1][i] + bf_;
        const float ov = tot[2][i] + bo;
        const float gv = tot[3][i] + bg;
        const float ig = 1.f / (1.f + __expf(-av));
        const float fg = 1.f / (1.f + __expf(-fv));
        const float og = 1.f / (1.f + __expf(-ov));
        const float gcl = fminf(fmaxf(gv, -20.f), 20.f);
        const float e2g = __expf(2.f * gcl);
        const float gg = (e2g - 1.f) / (e2g + 1.f);
        creg[i] = fg * creg[i] + ig * gg;
        const float ccl = fminf(fmaxf(creg[i], -20.f), 20.f);
        const float e2c = __expf(2.f * ccl);
        const float th = (e2c - 1.f) / (e2c + 1.f);
        const float hn = og * th;
        hW[(size_t)n * 1024 + u] = f2bf(hn);
        __builtin_nontemporal_store(hn, &out[((size_t)n * 64 + t) * 1024 + u]);
      }
    }
    if (t < 63) gbar(barcnt, ++phase * NBLK);   // barB: h(t+1) visible
  }
}

// ---------------- launch ----------------

extern "C" void kernel_launch(void* const* d_in, const int* in_sizes, int n_in,
                              void* d_out, int out_size, void* d_ws, size_t ws_size,
                              hipStream_t stream)
{
  const float* x     = (const float*)d_in[0];
  const float* A     = (const float*)d_in[1];
  const float* Wx    = (const float*)d_in[2];
  const float* Wh    = (const float*)d_in[3];
  const float* Wattn = (const float*)d_in[4];
  const float* b     = (const float*)d_in[5];
  float* out = (float*)d_out;
  char* ws = (char*)d_ws;

  short*    W3T    = (short*)(ws + 0);            // 25165824
  short*    Abf    = (short*)(ws + 25165824);     //  4194304
  short*    xbf    = (short*)(ws + 29360128);     // 16777216
  short*    hbuf   = (short*)(ws + 46137344);     //   524288 (2 parities)
  short*    abuf   = (short*)(ws + 46661632);     //   262144
  float*    cbuf   = (float*)(ws + 46923776);     //   524288
  unsigned* barcnt = (unsigned*)(ws + 47448064);  //        4

  hipLaunchKernelGGL(k_wt,   dim3(48 * 64), dim3(256), 0, stream, Wx, Wh, Wattn, W3T);
  hipLaunchKernelGGL(k_cast, dim3(2097152 / 256), dim3(256), 0, stream, x, xbf, 2097152);
  hipLaunchKernelGGL(k_cast, dim3(524288 / 256),  dim3(256), 0, stream, A, Abf, 524288);
  hipLaunchKernelGGL(k_init, dim3(512), dim3(256), 0, stream, A, cbuf, hbuf, barcnt);
  hipLaunchKernelGGL(k_loop, dim3(256), dim3(512), 0, stream,
                     W3T, xbf, Abf, hbuf, abuf, cbuf, b, out, barcnt);
}

// Round 6
// 2482.612 us; speedup vs baseline: 1.7556x; 1.7556x over previous
//
#include <hip/hip_runtime.h>
#include <stdint.h>
#include <math.h>

typedef __attribute__((ext_vector_type(8))) short short8;
typedef __attribute__((ext_vector_type(4))) short short4v;
typedef __attribute__((ext_vector_type(4))) float f32x4;

__device__ __forceinline__ short f2bf(float f){
  union { float f; uint32_t u; } x; x.f = f;
  uint32_t r = x.u + 0x7fffu + ((x.u >> 16) & 1u);
  return (short)(r >> 16);
}
__device__ __forceinline__ float bf2f(short s){
  union { uint32_t u; float f; } x; x.u = ((uint32_t)(uint16_t)s) << 16;
  return x.f;
}

// ---------------- grid barrier: store-flags + all-poll-all ----------------
// Arrival: one release-ordered store per block to its own 64B-strided flag.
// Wait: wave 0 polls all 256 flags (4 per lane, relaxed), then one acquire fence.
// Fence structure (threadfence on both sides) identical to R4/R5 (proven correct).
__device__ __forceinline__ void gbar2(unsigned* flags, int bid, unsigned phase){
  __syncthreads();
  const int tid = threadIdx.x;
  if (tid == 0){
    __threadfence();
    __hip_atomic_store(&flags[bid * 16], phase, __ATOMIC_RELAXED, __HIP_MEMORY_SCOPE_AGENT);
  }
  if (tid < 64){
    for (;;){
      unsigned mn = 0xffffffffu;
      #pragma unroll
      for (int i = 0; i < 4; ++i){
        unsigned v = __hip_atomic_load(&flags[(tid * 4 + i) * 16], __ATOMIC_RELAXED,
                                       __HIP_MEMORY_SCOPE_AGENT);
        mn = v < mn ? v : mn;
      }
      if (__all(mn >= phase)) break;
      __builtin_amdgcn_s_sleep(4);
    }
    if (tid == 0) __threadfence();
  }
  __syncthreads();
}

// ---------------- prep kernels ----------------

// Transposed, bf16, concatenated weights: W3T[j][k], j in [0,4096), k in [0,3072)
__global__ __launch_bounds__(256) void k_wt(const float* __restrict__ Wx,
                                            const float* __restrict__ Wh,
                                            const float* __restrict__ Wattn,
                                            short* __restrict__ W3T){
  __shared__ float tile[64][65];
  int bk = blockIdx.x % 48, bj = blockIdx.x / 48;
  int tx = threadIdx.x & 63, ty = threadIdx.x >> 6;
  int k0 = bk * 64, j0 = bj * 64;
  #pragma unroll
  for (int i = 0; i < 16; ++i){
    int kk = ty * 16 + i;
    int k = k0 + kk;
    const float* src = (k < 1024) ? (Wx + (size_t)k * 4096)
                     : (k < 2048) ? (Wh + (size_t)(k - 1024) * 4096)
                                  : (Wattn + (size_t)(k - 2048) * 4096);
    tile[kk][tx] = src[j0 + tx];
  }
  __syncthreads();
  #pragma unroll
  for (int i = 0; i < 16; ++i){
    int jj = ty * 16 + i;
    W3T[(size_t)(j0 + jj) * 3072 + k0 + tx] = f2bf(tile[tx][jj]);
  }
}

__global__ __launch_bounds__(256) void k_cast(const float* __restrict__ in,
                                              short* __restrict__ out, int n4){
  int i = blockIdx.x * 256 + threadIdx.x;
  if (i >= n4) return;
  float4 v = ((const float4*)in)[i];
  short4v o; o[0] = f2bf(v.x); o[1] = f2bf(v.y); o[2] = f2bf(v.z); o[3] = f2bf(v.w);
  *(short4v*)(out + (size_t)i * 4) = o;
}

// h0 = c0 = mean over L=16 of A; zero the barrier flags
__global__ __launch_bounds__(256) void k_init(const float* __restrict__ A,
                                              float* __restrict__ c,
                                              short* __restrict__ hb0,
                                              unsigned* __restrict__ flags){
  int idx = blockIdx.x * 256 + threadIdx.x;    // N*H = 131072
  if (idx < 4096) flags[idx] = 0u;
  const float* p = A + (size_t)idx * 16;
  float s = 0.f;
  #pragma unroll
  for (int l = 0; l < 16; ++l) s += p[l];
  s *= (1.f / 16.f);
  c[idx] = s;
  hb0[idx] = f2bf(s);
}

// ---------------- xwx precompute (R2-proven 128x128 tile GEMM, bf16 out) ----
typedef const __attribute__((address_space(1))) uint32_t* gas1_t;
typedef __attribute__((address_space(3))) uint32_t* las3_t;

__global__ __launch_bounds__(256) void k_xwx(const short* __restrict__ xbf,
                                             const short* __restrict__ W3T,
                                             short* __restrict__ xwx){
  __shared__ short ldsA[128 * 64];
  __shared__ short ldsB[128 * 64];
  const int tid  = threadIdx.x;
  const int lane = tid & 63;
  const int wave = tid >> 6;

  const int orig = blockIdx.x;
  const int wg = (orig & 7) * 256 + (orig >> 3);
  const int n_t = wg >> 6;
  const int m_t = wg & 63;
  const int m0 = m_t * 128;
  const int n0 = n_t * 128;

  const int ra = lane & 15;
  const int q  = lane >> 4;

  f32x4 acc[4][4];
  #pragma unroll
  for (int mf = 0; mf < 4; ++mf)
    #pragma unroll
    for (int jf = 0; jf < 4; ++jf) acc[mf][jf] = f32x4{0.f,0.f,0.f,0.f};

  const int wm = wave >> 1;
  const int wn = wave & 1;

  for (int kt = 0; kt < 16; ++kt){
    const int kb = kt * 64;
    #pragma unroll
    for (int r = 0; r < 4; ++r){
      int id = (wave * 4 + r) * 64 + lane;
      int row = id >> 3, c = id & 7;
      int csrc = c ^ (row & 7);
      const short* src = xbf + (size_t)(m0 + row) * 1024 + kb + csrc * 8;
      short* dst = ldsA + (wave * 4 + r) * 512;
      __builtin_amdgcn_global_load_lds((gas1_t)(const void*)src, (las3_t)(void*)dst, 16, 0, 0);
    }
    #pragma unroll
    for (int r = 0; r < 4; ++r){
      int id = (wave * 4 + r) * 64 + lane;
      int row = id >> 3, c = id & 7;
      int csrc = c ^ (row & 7);
      const short* src = W3T + (size_t)(n0 + row) * 3072 + kb + csrc * 8;
      short* dst = ldsB + (wave * 4 + r) * 512;
      __builtin_amdgcn_global_load_lds((gas1_t)(const void*)src, (las3_t)(void*)dst, 16, 0, 0);
    }
    asm volatile("s_waitcnt vmcnt(0)" ::: "memory");
    __syncthreads();

    #pragma unroll
    for (int kk = 0; kk < 64; kk += 32){
      const int cc = (kk >> 3) + q;
      short8 af[4], bfr[4];
      #pragma unroll
      for (int mf = 0; mf < 4; ++mf){
        int row = wm * 64 + mf * 16 + ra;
        af[mf] = *(const short8*)(ldsA + row * 64 + ((cc ^ (row & 7)) << 3));
      }
      #pragma unroll
      for (int jf = 0; jf < 4; ++jf){
        int row = wn * 64 + jf * 16 + ra;
        bfr[jf] = *(const short8*)(ldsB + row * 64 + ((cc ^ (row & 7)) << 3));
      }
      #pragma unroll
      for (int mf = 0; mf < 4; ++mf)
        #pragma unroll
        for (int jf = 0; jf < 4; ++jf)
          acc[mf][jf] = __builtin_amdgcn_mfma_f32_16x16x32_bf16(af[mf], bfr[jf], acc[mf][jf], 0, 0, 0);
    }
    __syncthreads();
  }

  #pragma unroll
  for (int mf = 0; mf < 4; ++mf)
    #pragma unroll
    for (int jf = 0; jf < 4; ++jf)
      #pragma unroll
      for (int i = 0; i < 4; ++i){
        int row = m0 + wm * 64 + mf * 16 + q * 4 + i;
        int col = n0 + wn * 64 + jf * 16 + ra;
        xwx[(size_t)row * 4096 + col] = f2bf(acc[mf][jf][i]);
      }
}

// ---------------- persistent recurrence kernel ----------------
// 256 blocks x 512 threads, 1 block/CU (LDS 145KB forces it).
// Block: mh = bid&1 (64 n-rows), jb = bid>>1 -> u0 = jb*8; j-set = 4 gates x 8 u.
// W(h|attn) slice [32 j][2048 k] lives in LDS for all 64 steps (XOR-swizzled).
// 8 waves = (mf2 = wave&1: 32-row half) x (kh = wave>>1: 512-k quarter).
// Reduction: 5-stage LDS pair-reduce; epilogue: 1 thread per (n,u) cell, c in reg.
__global__ __launch_bounds__(512, 1) void k_loop(
    const short* __restrict__ W3T,
    const short* __restrict__ Abf,     // [128][1024][16] bf16
    short* __restrict__ hbuf,          // [2][128][1024] bf16
    short* __restrict__ abuf,          // [128][1024] bf16
    const float* __restrict__ cbuf,    // [128][1024] f32
    const short* __restrict__ xwx,     // [8192][4096] bf16
    const float* __restrict__ bias,    // [4096] f32
    float* __restrict__ out,           // [128][64][1024] f32
    unsigned* __restrict__ flags)
{
  __shared__ short Wl[65536];          // 131072 B: [jf2][ra16][kc256] 16B chunks, swizzled
  __shared__ float redu[4096];         // 16 KB reduce/fin union
  __shared__ float sred[8][16];

  const int tid  = threadIdx.x;
  const int lane = tid & 63;
  const int wave = tid >> 6;
  const int bid  = blockIdx.x;
  const int mh   = bid & 1;
  const int jb   = bid >> 1;           // 0..127
  const int u0   = jb * 8;
  const int ra   = lane & 15;
  const int q    = lane >> 4;
  const int mf2  = wave & 1;           // row half within block (32 rows)
  const int kh   = wave >> 1;          // K quarter (512)

  // ---- prologue: W slice -> LDS (once). j(jf,rr) = (jf*2+(rr>>3))*1024 + u0 + (rr&7)
  #pragma unroll
  for (int it = 0; it < 16; ++it){
    int c16 = it * 512 + tid;          // 0..8191
    int jl = c16 >> 8;                 // 0..31
    int kc = c16 & 255;
    int jf = jl >> 4, rr = jl & 15;
    int j = (jf * 2 + (rr >> 3)) * 1024 + u0 + (rr & 7);
    short8 v = *(const short8*)(W3T + (size_t)j * 3072 + 1024 + kc * 8);
    int pc = (jf * 16 + rr) * 256 + (kc ^ (rr & 7));
    *(short8*)(Wl + pc * 8) = v;
  }

  // ---- per-thread LSTM cell (n_loc, uu); c and bias in registers for all steps
  const int n_loc = tid >> 3, uu = tid & 7;
  const int cn = mh * 64 + n_loc;
  const int cu = u0 + uu;
  float creg = cbuf[(size_t)cn * 1024 + cu];
  const float b0 = bias[cu], b1 = bias[1024 + cu], b2 = bias[2048 + cu], b3 = bias[3072 + cu];
  const int mf2p = n_loc >> 5, mm = (n_loc >> 4) & 1, rr_ = n_loc & 15;
  __syncthreads();

  unsigned phase = 0;

  for (int t = 0; t < 64; ++t){
    const short* hRp = hbuf + (size_t)(t & 1) * 131072;
    short*       hWp = hbuf + (size_t)((t + 1) & 1) * 131072;

    // ---------- phase A: attention (blocks 0..127, one per n) ----------
    short8 a00, a01, a10, a11; float h0v = 0.f, h1v = 0.f;
    if (bid < 128){
      const int n = bid;
      h0v = bf2f(hRp[n * 1024 + tid * 2 + 0]);
      h1v = bf2f(hRp[n * 1024 + tid * 2 + 1]);
      const short8* ap0 = (const short8*)(Abf + ((size_t)n * 1024 + tid * 2 + 0) * 16);
      const short8* ap1 = (const short8*)(Abf + ((size_t)n * 1024 + tid * 2 + 1) * 16);
      a00 = ap0[0]; a01 = ap0[1]; a10 = ap1[0]; a11 = ap1[1];
      float sc[16];
      #pragma unroll
      for (int l = 0; l < 8; ++l){
        sc[l]     = h0v * bf2f(a00[l]) + h1v * bf2f(a10[l]);
        sc[8 + l] = h0v * bf2f(a01[l]) + h1v * bf2f(a11[l]);
      }
      #pragma unroll
      for (int off = 1; off < 64; off <<= 1)
        #pragma unroll
        for (int l = 0; l < 16; ++l) sc[l] += __shfl_xor(sc[l], off);
      if (lane == 0)
        #pragma unroll
        for (int l = 0; l < 16; ++l) sred[wave][l] = sc[l];
    }
    __syncthreads();
    if (bid < 128){
      const int n = bid;
      float s[16], mx = -1e30f, sum = 0.f;
      #pragma unroll
      for (int l = 0; l < 16; ++l){
        float v = sred[0][l];
        #pragma unroll
        for (int w = 1; w < 8; ++w) v += sred[w][l];
        s[l] = v * 0.03125f;
        mx = fmaxf(mx, s[l]);
      }
      #pragma unroll
      for (int l = 0; l < 16; ++l){ s[l] = __expf(s[l] - mx); sum += s[l]; }
      const float inv = 1.f / sum;
      float ac0 = 0.f, ac1 = 0.f;
      #pragma unroll
      for (int l = 0; l < 8; ++l){
        ac0 += s[l] * bf2f(a00[l]) + s[8 + l] * bf2f(a01[l]);
        ac1 += s[l] * bf2f(a10[l]) + s[8 + l] * bf2f(a11[l]);
      }
      abuf[n * 1024 + tid * 2 + 0] = f2bf(ac0 * inv);
      abuf[n * 1024 + tid * 2 + 1] = f2bf(ac1 * inv);
    }
    gbar2(flags, bid, ++phase);        // attn + h visible everywhere

    // xwx prefetch for this thread's cell (hides under GEMM)
    const short* xp = xwx + ((size_t)cn * 64 + t) * 4096;
    const short xw0 = xp[cu], xw1 = xp[1024 + cu], xw2 = xp[2048 + cu], xw3 = xp[3072 + cu];

    // ---------- phase B: GEMM. wave: rows mf2*32+[0,32), k kh*512+[0,512) ----------
    f32x4 acc[2][2];                   // [m-frag][j-frag]
    acc[0][0] = f32x4{0.f,0.f,0.f,0.f}; acc[0][1] = f32x4{0.f,0.f,0.f,0.f};
    acc[1][0] = f32x4{0.f,0.f,0.f,0.f}; acc[1][1] = f32x4{0.f,0.f,0.f,0.f};

    auto loadA = [&](int ks, int m) -> short8 {
      const int k = kh * 512 + ks * 32 + q * 8;
      const int row = mh * 64 + mf2 * 32 + m * 16 + ra;
      const short* p = (kh < 2) ? (hRp + row * 1024 + k)
                                : (abuf + row * 1024 + (k - 1024));
      return *(const short8*)p;
    };

    short8 Ac0 = loadA(0, 0), Ac1 = loadA(0, 1), An0, An1;
    #pragma unroll
    for (int ks = 0; ks < 16; ++ks){
      if (ks < 15){ An0 = loadA(ks + 1, 0); An1 = loadA(ks + 1, 1); }
      const int kcg = kh * 64 + ks * 4 + q;
      const int sw = (kcg ^ (ra & 7));
      short8 B0 = *(const short8*)(Wl + ((ra * 256) + sw) * 8);
      short8 B1 = *(const short8*)(Wl + (((16 + ra) * 256) + sw) * 8);
      acc[0][0] = __builtin_amdgcn_mfma_f32_16x16x32_bf16(Ac0, B0, acc[0][0], 0, 0, 0);
      acc[0][1] = __builtin_amdgcn_mfma_f32_16x16x32_bf16(Ac0, B1, acc[0][1], 0, 0, 0);
      acc[1][0] = __builtin_amdgcn_mfma_f32_16x16x32_bf16(Ac1, B0, acc[1][0], 0, 0, 0);
      acc[1][1] = __builtin_amdgcn_mfma_f32_16x16x32_bf16(Ac1, B1, acc[1][1], 0, 0, 0);
      if (ks < 15){ Ac0 = An0; Ac1 = An1; }
    }

    // ---------- 5-stage reduction over kh (pairs), then fin layout ----------
    auto ridx = [&](int m2, int khq, int m, int jf) -> float* {
      return &redu[((((m2 * 2 + khq) * 2 + m) * 2 + jf) * 64 + lane) * 4];
    };
    if (kh & 1){                        // S1: kh 1,3 write
      *(f32x4*)ridx(mf2, kh >> 1, 0, 0) = acc[0][0];
      *(f32x4*)ridx(mf2, kh >> 1, 0, 1) = acc[0][1];
      *(f32x4*)ridx(mf2, kh >> 1, 1, 0) = acc[1][0];
      *(f32x4*)ridx(mf2, kh >> 1, 1, 1) = acc[1][1];
    }
    __syncthreads();
    if (!(kh & 1)){                     // S2: kh 0,2 add partner
      acc[0][0] += *(const f32x4*)ridx(mf2, kh >> 1, 0, 0);
      acc[0][1] += *(const f32x4*)ridx(mf2, kh >> 1, 0, 1);
      acc[1][0] += *(const f32x4*)ridx(mf2, kh >> 1, 1, 0);
      acc[1][1] += *(const f32x4*)ridx(mf2, kh >> 1, 1, 1);
    }
    __syncthreads();
    if (kh == 2){                       // S3
      *(f32x4*)ridx(mf2, 0, 0, 0) = acc[0][0];
      *(f32x4*)ridx(mf2, 0, 0, 1) = acc[0][1];
      *(f32x4*)ridx(mf2, 0, 1, 0) = acc[1][0];
      *(f32x4*)ridx(mf2, 0, 1, 1) = acc[1][1];
    }
    __syncthreads();
    if (kh == 0){                       // S4
      acc[0][0] += *(const f32x4*)ridx(mf2, 0, 0, 0);
      acc[0][1] += *(const f32x4*)ridx(mf2, 0, 0, 1);
      acc[1][0] += *(const f32x4*)ridx(mf2, 0, 1, 0);
      acc[1][1] += *(const f32x4*)ridx(mf2, 0, 1, 1);
    }
    __syncthreads();
    if (kh == 0){                       // S5: write fin[mf2][m][jf][ra][q*4+i]
      #pragma unroll
      for (int m = 0; m < 2; ++m)
        #pragma unroll
        for (int jf = 0; jf < 2; ++jf)
          #pragma unroll
          for (int i = 0; i < 4; ++i)
            redu[((((mf2 * 2 + m) * 2 + jf) * 16 + ra) * 16) + q * 4 + i] = acc[m][jf][i];
    }
    __syncthreads();

    // ---------- epilogue: 1 thread per (n,u) cell ----------
    {
      auto fidx = [&](int jf, int rag) -> float {
        return redu[((((mf2p * 2 + mm) * 2 + jf) * 16 + rag) * 16) + rr_];
      };
      const float av = fidx(0, uu)     + bf2f(xw0) + b0;
      const float fv = fidx(0, uu + 8) + bf2f(xw1) + b1;
      const float ov = fidx(1, uu)     + bf2f(xw2) + b2;
      const float gv = fidx(1, uu + 8) + bf2f(xw3) + b3;
      const float ig = 1.f / (1.f + __expf(-av));
      const float fg = 1.f / (1.f + __expf(-fv));
      const float og = 1.f / (1.f + __expf(-ov));
      const float gcl = fminf(fmaxf(gv, -20.f), 20.f);
      const float e2g = __expf(2.f * gcl);
      const float gg = (e2g - 1.f) / (e2g + 1.f);
      creg = fg * creg + ig * gg;
      const float ccl = fminf(fmaxf(creg, -20.f), 20.f);
      const float e2c = __expf(2.f * ccl);
      const float th = (e2c - 1.f) / (e2c + 1.f);
      const float hn = og * th;
      hWp[(size_t)cn * 1024 + cu] = f2bf(hn);
      __builtin_nontemporal_store(hn, &out[((size_t)cn * 64 + t) * 1024 + cu]);
    }
    if (t < 63) gbar2(flags, bid, ++phase);   // h(t+1) visible
  }
}

// ---------------- launch ----------------

extern "C" void kernel_launch(void* const* d_in, const int* in_sizes, int n_in,
                              void* d_out, int out_size, void* d_ws, size_t ws_size,
                              hipStream_t stream)
{
  const float* x     = (const float*)d_in[0];
  const float* A     = (const float*)d_in[1];
  const float* Wx    = (const float*)d_in[2];
  const float* Wh    = (const float*)d_in[3];
  const float* Wattn = (const float*)d_in[4];
  const float* b     = (const float*)d_in[5];
  float* out = (float*)d_out;
  char* ws = (char*)d_ws;

  short*    W3T   = (short*)(ws + 0);             // 25165824
  short*    Abf   = (short*)(ws + 25165824);      //  4194304
  short*    xbf   = (short*)(ws + 29360128);      // 16777216
  short*    hbuf  = (short*)(ws + 46137344);      //   524288 (2 parities)
  short*    abuf  = (short*)(ws + 46661632);      //   262144
  float*    cbuf  = (float*)(ws + 46923776);      //   524288
  short*    xwx   = (short*)(ws + 47448064);      // 67108864 (bf16)
  unsigned* flags = (unsigned*)(ws + 114556928);  //    16384

  hipLaunchKernelGGL(k_wt,   dim3(48 * 64), dim3(256), 0, stream, Wx, Wh, Wattn, W3T);
  hipLaunchKernelGGL(k_cast, dim3(2097152 / 256), dim3(256), 0, stream, x, xbf, 2097152);
  hipLaunchKernelGGL(k_cast, dim3(524288 / 256),  dim3(256), 0, stream, A, Abf, 524288);
  hipLaunchKernelGGL(k_init, dim3(512), dim3(256), 0, stream, A, cbuf, hbuf, flags);
  hipLaunchKernelGGL(k_xwx,  dim3(2048), dim3(256), 0, stream, xbf, W3T, xwx);
  hipLaunchKernelGGL(k_loop, dim3(256), dim3(512), 0, stream,
                     W3T, Abf, hbuf, abuf, cbuf, xwx, b, out, flags);
}

// Round 7
// 2261.665 us; speedup vs baseline: 1.9271x; 1.0977x over previous
//
#include <hip/hip_runtime.h>
#include <stdint.h>
#include <math.h>

typedef __attribute__((ext_vector_type(8))) short short8;
typedef __attribute__((ext_vector_type(4))) short short4v;
typedef __attribute__((ext_vector_type(4))) float f32x4;

__device__ __forceinline__ short f2bf(float f){
  union { float f; uint32_t u; } x; x.f = f;
  uint32_t r = x.u + 0x7fffu + ((x.u >> 16) & 1u);
  return (short)(r >> 16);
}
__device__ __forceinline__ float bf2f(short s){
  union { uint32_t u; float f; } x; x.u = ((uint32_t)(uint16_t)s) << 16;
  return x.f;
}

// ---------------- leader grid barrier ----------------
// Arrival: each block release-fences + stores its flag (monotonic phase).
// Block 0 wave 0 aggregates all 256 flags (4/lane), publishes `go`.
// Other blocks: single lane polls `go`, then acquire fence.
__device__ __forceinline__ void gbar3(unsigned* flags, unsigned* go, int bid, unsigned phase){
  __syncthreads();
  const int tid = threadIdx.x;
  if (tid == 0){
    __threadfence();
    __hip_atomic_store(&flags[bid * 16], phase, __ATOMIC_RELAXED, __HIP_MEMORY_SCOPE_AGENT);
  }
  if (bid == 0){
    if (tid < 64){
      for (;;){
        unsigned mn = 0xffffffffu;
        #pragma unroll
        for (int i = 0; i < 4; ++i){
          unsigned v = __hip_atomic_load(&flags[(tid * 4 + i) * 16], __ATOMIC_RELAXED,
                                         __HIP_MEMORY_SCOPE_AGENT);
          mn = v < mn ? v : mn;
        }
        if (__all(mn >= phase)) break;
        __builtin_amdgcn_s_sleep(2);
      }
      if (tid == 0){
        __threadfence();   // full fence: orders observation, serves as block0 acquire
        __hip_atomic_store(go, phase, __ATOMIC_RELAXED, __HIP_MEMORY_SCOPE_AGENT);
      }
    }
  } else {
    if (tid == 0){
      while (__hip_atomic_load(go, __ATOMIC_RELAXED, __HIP_MEMORY_SCOPE_AGENT) < phase)
        __builtin_amdgcn_s_sleep(1);
      __threadfence();     // acquire
    }
  }
  __syncthreads();
}

// ---------------- prep kernels ----------------

// Transposed, bf16, concatenated weights: W3T[j][k], j in [0,4096), k in [0,3072)
__global__ __launch_bounds__(256) void k_wt(const float* __restrict__ Wx,
                                            const float* __restrict__ Wh,
                                            const float* __restrict__ Wattn,
                                            short* __restrict__ W3T){
  __shared__ float tile[64][65];
  int bk = blockIdx.x % 48, bj = blockIdx.x / 48;
  int tx = threadIdx.x & 63, ty = threadIdx.x >> 6;
  int k0 = bk * 64, j0 = bj * 64;
  #pragma unroll
  for (int i = 0; i < 16; ++i){
    int kk = ty * 16 + i;
    int k = k0 + kk;
    const float* src = (k < 1024) ? (Wx + (size_t)k * 4096)
                     : (k < 2048) ? (Wh + (size_t)(k - 1024) * 4096)
                                  : (Wattn + (size_t)(k - 2048) * 4096);
    tile[kk][tx] = src[j0 + tx];
  }
  __syncthreads();
  #pragma unroll
  for (int i = 0; i < 16; ++i){
    int jj = ty * 16 + i;
    W3T[(size_t)(j0 + jj) * 3072 + k0 + tx] = f2bf(tile[tx][jj]);
  }
}

__global__ __launch_bounds__(256) void k_cast(const float* __restrict__ in,
                                              short* __restrict__ out, int n4){
  int i = blockIdx.x * 256 + threadIdx.x;
  if (i >= n4) return;
  float4 v = ((const float4*)in)[i];
  short4v o; o[0] = f2bf(v.x); o[1] = f2bf(v.y); o[2] = f2bf(v.z); o[3] = f2bf(v.w);
  *(short4v*)(out + (size_t)i * 4) = o;
}

// h0 = c0 = mean over L=16 of A; zero barrier flags + go
__global__ __launch_bounds__(256) void k_init(const float* __restrict__ A,
                                              float* __restrict__ c,
                                              short* __restrict__ hb0,
                                              unsigned* __restrict__ flags){
  int idx = blockIdx.x * 256 + threadIdx.x;    // N*H = 131072
  if (idx < 8192) flags[idx] = 0u;
  const float* p = A + (size_t)idx * 16;
  float s = 0.f;
  #pragma unroll
  for (int l = 0; l < 16; ++l) s += p[l];
  s *= (1.f / 16.f);
  c[idx] = s;
  hb0[idx] = f2bf(s);
}

// ---------------- xwx precompute (128x128 tile GEMM, bf16 out) ----
typedef const __attribute__((address_space(1))) uint32_t* gas1_t;
typedef __attribute__((address_space(3))) uint32_t* las3_t;

__global__ __launch_bounds__(256) void k_xwx(const short* __restrict__ xbf,
                                             const short* __restrict__ W3T,
                                             short* __restrict__ xwx){
  __shared__ short ldsA[128 * 64];
  __shared__ short ldsB[128 * 64];
  const int tid  = threadIdx.x;
  const int lane = tid & 63;
  const int wave = tid >> 6;

  const int orig = blockIdx.x;
  const int wg = (orig & 7) * 256 + (orig >> 3);
  const int n_t = wg >> 6;
  const int m_t = wg & 63;
  const int m0 = m_t * 128;
  const int n0 = n_t * 128;

  const int ra = lane & 15;
  const int q  = lane >> 4;

  f32x4 acc[4][4];
  #pragma unroll
  for (int mf = 0; mf < 4; ++mf)
    #pragma unroll
    for (int jf = 0; jf < 4; ++jf) acc[mf][jf] = f32x4{0.f,0.f,0.f,0.f};

  const int wm = wave >> 1;
  const int wn = wave & 1;

  for (int kt = 0; kt < 16; ++kt){
    const int kb = kt * 64;
    #pragma unroll
    for (int r = 0; r < 4; ++r){
      int id = (wave * 4 + r) * 64 + lane;
      int row = id >> 3, c = id & 7;
      int csrc = c ^ (row & 7);
      const short* src = xbf + (size_t)(m0 + row) * 1024 + kb + csrc * 8;
      short* dst = ldsA + (wave * 4 + r) * 512;
      __builtin_amdgcn_global_load_lds((gas1_t)(const void*)src, (las3_t)(void*)dst, 16, 0, 0);
    }
    #pragma unroll
    for (int r = 0; r < 4; ++r){
      int id = (wave * 4 + r) * 64 + lane;
      int row = id >> 3, c = id & 7;
      int csrc = c ^ (row & 7);
      const short* src = W3T + (size_t)(n0 + row) * 3072 + kb + csrc * 8;
      short* dst = ldsB + (wave * 4 + r) * 512;
      __builtin_amdgcn_global_load_lds((gas1_t)(const void*)src, (las3_t)(void*)dst, 16, 0, 0);
    }
    asm volatile("s_waitcnt vmcnt(0)" ::: "memory");
    __syncthreads();

    #pragma unroll
    for (int kk = 0; kk < 64; kk += 32){
      const int cc = (kk >> 3) + q;
      short8 af[4], bfr[4];
      #pragma unroll
      for (int mf = 0; mf < 4; ++mf){
        int row = wm * 64 + mf * 16 + ra;
        af[mf] = *(const short8*)(ldsA + row * 64 + ((cc ^ (row & 7)) << 3));
      }
      #pragma unroll
      for (int jf = 0; jf < 4; ++jf){
        int row = wn * 64 + jf * 16 + ra;
        bfr[jf] = *(const short8*)(ldsB + row * 64 + ((cc ^ (row & 7)) << 3));
      }
      #pragma unroll
      for (int mf = 0; mf < 4; ++mf)
        #pragma unroll
        for (int jf = 0; jf < 4; ++jf)
          acc[mf][jf] = __builtin_amdgcn_mfma_f32_16x16x32_bf16(af[mf], bfr[jf], acc[mf][jf], 0, 0, 0);
    }
    __syncthreads();
  }

  #pragma unroll
  for (int mf = 0; mf < 4; ++mf)
    #pragma unroll
    for (int jf = 0; jf < 4; ++jf)
      #pragma unroll
      for (int i = 0; i < 4; ++i){
        int row = m0 + wm * 64 + mf * 16 + q * 4 + i;
        int col = n0 + wn * 64 + jf * 16 + ra;
        xwx[(size_t)row * 4096 + col] = f2bf(acc[mf][jf][i]);
      }
}

// ---------------- persistent recurrence kernel ----------------
// 256 blocks x 512 threads, 1 block/CU. Block: mh = bid&1 (64 n), jb = bid>>1
// (u0 = jb*8; 32 j = 4 gates x 8 u). W slice [32j][2048k] in LDS all 64 steps.
// 8 waves = (mf2 = wave&1) x (kh = wave>>1: 512-k quarter). Leader grid barrier.
__global__ __launch_bounds__(512, 1) void k_loop(
    const short* __restrict__ W3T,
    const short* __restrict__ Abf,     // [128][1024][16] bf16
    short* __restrict__ hbuf,          // [2][128][1024] bf16
    short* __restrict__ abuf,          // [128][1024] bf16
    const float* __restrict__ cbuf,    // [128][1024] f32
    const short* __restrict__ xwx,     // [8192][4096] bf16
    const float* __restrict__ bias,    // [4096] f32
    float* __restrict__ out,           // [128][64][1024] f32
    unsigned* __restrict__ flags)
{
  __shared__ short Wl[65536];          // 128 KB: [j32][kc256] 16B chunks, XOR-swizzled
  __shared__ float redu[4096];         // 16 KB reduce + fin union
  __shared__ float sred[8][16];

  unsigned* go = flags + 4096;

  const int tid  = threadIdx.x;
  const int lane = tid & 63;
  const int wave = tid >> 6;
  const int bid  = blockIdx.x;
  const int mh   = bid & 1;
  const int jb   = bid >> 1;           // 0..127
  const int u0   = jb * 8;
  const int ra   = lane & 15;
  const int q    = lane >> 4;
  const int mf2  = wave & 1;           // row half within block (32 rows)
  const int kh   = wave >> 1;          // K quarter (512)

  // ---- prologue: W slice -> LDS (once). j(jf,rr) = (jf*2+(rr>>3))*1024 + u0 + (rr&7)
  #pragma unroll
  for (int it = 0; it < 16; ++it){
    int c16 = it * 512 + tid;          // 0..8191
    int jl = c16 >> 8;                 // 0..31
    int kc = c16 & 255;
    int jf = jl >> 4, rr = jl & 15;
    int j = (jf * 2 + (rr >> 3)) * 1024 + u0 + (rr & 7);
    short8 v = *(const short8*)(W3T + (size_t)j * 3072 + 1024 + kc * 8);
    int pc = (jf * 16 + rr) * 256 + (kc ^ (rr & 7));
    *(short8*)(Wl + pc * 8) = v;
  }

  // ---- hoisted constants: attention A-fragments (step-invariant!)
  short8 a00{}, a01{}, a10{}, a11{};
  if (bid < 128){
    const short8* ap0 = (const short8*)(Abf + ((size_t)bid * 1024 + tid * 2 + 0) * 16);
    const short8* ap1 = (const short8*)(Abf + ((size_t)bid * 1024 + tid * 2 + 1) * 16);
    a00 = ap0[0]; a01 = ap0[1]; a10 = ap1[0]; a11 = ap1[1];
  }

  // ---- per-thread LSTM cell (n_loc, uu); c and bias in registers for all steps
  const int n_loc = tid >> 3, uu = tid & 7;
  const int cn = mh * 64 + n_loc;
  const int cu = u0 + uu;
  float creg = cbuf[(size_t)cn * 1024 + cu];
  const float b0 = bias[cu], b1 = bias[1024 + cu], b2 = bias[2048 + cu], b3 = bias[3072 + cu];
  __syncthreads();

  unsigned phase = 0;

  for (int t = 0; t < 64; ++t){
    const short* hRp = hbuf + (size_t)(t & 1) * 131072;
    short*       hWp = hbuf + (size_t)((t + 1) & 1) * 131072;

    // ---------- phase A: attention (blocks 0..127, one per n) ----------
    float h0v = 0.f, h1v = 0.f;
    if (bid < 128){
      unsigned hv2 = *(const unsigned*)(hRp + bid * 1024 + tid * 2);
      h0v = bf2f((short)(hv2 & 0xffffu));
      h1v = bf2f((short)(hv2 >> 16));
      float sc[16];
      #pragma unroll
      for (int l = 0; l < 8; ++l){
        sc[l]     = h0v * bf2f(a00[l]) + h1v * bf2f(a10[l]);
        sc[8 + l] = h0v * bf2f(a01[l]) + h1v * bf2f(a11[l]);
      }
      #pragma unroll
      for (int off = 1; off < 64; off <<= 1)
        #pragma unroll
        for (int l = 0; l < 16; ++l) sc[l] += __shfl_xor(sc[l], off);
      if (lane == 0)
        #pragma unroll
        for (int l = 0; l < 16; ++l) sred[wave][l] = sc[l];
    }
    __syncthreads();
    if (bid < 128){
      float s[16], mx = -1e30f, sum = 0.f;
      #pragma unroll
      for (int l = 0; l < 16; ++l){
        float v = sred[0][l];
        #pragma unroll
        for (int w = 1; w < 8; ++w) v += sred[w][l];
        s[l] = v * 0.03125f;
        mx = fmaxf(mx, s[l]);
      }
      #pragma unroll
      for (int l = 0; l < 16; ++l){ s[l] = __expf(s[l] - mx); sum += s[l]; }
      const float inv = 1.f / sum;
      float ac0 = 0.f, ac1 = 0.f;
      #pragma unroll
      for (int l = 0; l < 8; ++l){
        ac0 += s[l] * bf2f(a00[l]) + s[8 + l] * bf2f(a01[l]);
        ac1 += s[l] * bf2f(a10[l]) + s[8 + l] * bf2f(a11[l]);
      }
      abuf[bid * 1024 + tid * 2 + 0] = f2bf(ac0 * inv);
      abuf[bid * 1024 + tid * 2 + 1] = f2bf(ac1 * inv);
    }

    // ---------- pre-barrier prefetch (hides latency under barA) ----------
    // xwx is constant after prep; h (kh<2 operand) is valid since barB of t-1.
    const short* xp = xwx + ((size_t)cn * 64 + t) * 4096;
    const short xw0 = xp[cu], xw1 = xp[1024 + cu], xw2 = xp[2048 + cu], xw3 = xp[3072 + cu];

    auto loadA = [&](int ks, int m) -> short8 {
      const int kk = ks * 32 + q * 8;
      const int row = mh * 64 + mf2 * 32 + m * 16 + ra;
      const short* p = (kh < 2) ? (hRp + row * 1024 + kh * 512 + kk)
                                : (abuf + row * 1024 + (kh - 2) * 512 + kk);
      return *(const short8*)p;
    };
    auto loadB = [&](int ks, int jf) -> short8 {
      const int kcg = kh * 64 + ks * 4 + q;
      const int sw = kcg ^ (ra & 7);
      return *(const short8*)(Wl + (((jf * 16 + ra) * 256) + sw) * 8);
    };

    short8 Ab[4][2], Bb[2][2];
    Bb[0][0] = loadB(0, 0); Bb[0][1] = loadB(0, 1);
    Bb[1][0] = loadB(1, 0); Bb[1][1] = loadB(1, 1);
    if (kh < 2){
      #pragma unroll
      for (int p = 0; p < 4; ++p){ Ab[p][0] = loadA(p, 0); Ab[p][1] = loadA(p, 1); }
    }

    gbar3(flags, go, bid, ++phase);    // barA: attn + h visible everywhere

    if (kh >= 2){
      #pragma unroll
      for (int p = 0; p < 4; ++p){ Ab[p][0] = loadA(p, 0); Ab[p][1] = loadA(p, 1); }
    }

    // ---------- phase B: GEMM, 16 K-iters, A 4-deep / B 2-deep prefetch ----------
    f32x4 acc[2][2];
    acc[0][0] = f32x4{0.f,0.f,0.f,0.f}; acc[0][1] = f32x4{0.f,0.f,0.f,0.f};
    acc[1][0] = f32x4{0.f,0.f,0.f,0.f}; acc[1][1] = f32x4{0.f,0.f,0.f,0.f};

    #pragma unroll
    for (int ks = 0; ks < 16; ++ks){
      short8 av0 = Ab[ks & 3][0], av1 = Ab[ks & 3][1];
      short8 bv0 = Bb[ks & 1][0], bv1 = Bb[ks & 1][1];
      if (ks < 12){ Ab[ks & 3][0] = loadA(ks + 4, 0); Ab[ks & 3][1] = loadA(ks + 4, 1); }
      if (ks < 14){ Bb[ks & 1][0] = loadB(ks + 2, 0); Bb[ks & 1][1] = loadB(ks + 2, 1); }
      acc[0][0] = __builtin_amdgcn_mfma_f32_16x16x32_bf16(av0, bv0, acc[0][0], 0, 0, 0);
      acc[0][1] = __builtin_amdgcn_mfma_f32_16x16x32_bf16(av0, bv1, acc[0][1], 0, 0, 0);
      acc[1][0] = __builtin_amdgcn_mfma_f32_16x16x32_bf16(av1, bv0, acc[1][0], 0, 0, 0);
      acc[1][1] = __builtin_amdgcn_mfma_f32_16x16x32_bf16(av1, bv1, acc[1][1], 0, 0, 0);
    }

    // ---------- reduction over kh (pairs) ----------
    auto ridx = [&](int m2, int khq, int m, int jf) -> float* {
      return &redu[((((m2 * 2 + khq) * 2 + m) * 2 + jf) * 64 + lane) * 4];
    };
    if (kh & 1){                        // S1: kh 1,3 write
      *(f32x4*)ridx(mf2, kh >> 1, 0, 0) = acc[0][0];
      *(f32x4*)ridx(mf2, kh >> 1, 0, 1) = acc[0][1];
      *(f32x4*)ridx(mf2, kh >> 1, 1, 0) = acc[1][0];
      *(f32x4*)ridx(mf2, kh >> 1, 1, 1) = acc[1][1];
    }
    __syncthreads();
    if (!(kh & 1)){                     // S2: kh 0,2 add partner
      acc[0][0] += *(const f32x4*)ridx(mf2, kh >> 1, 0, 0);
      acc[0][1] += *(const f32x4*)ridx(mf2, kh >> 1, 0, 1);
      acc[1][0] += *(const f32x4*)ridx(mf2, kh >> 1, 1, 0);
      acc[1][1] += *(const f32x4*)ridx(mf2, kh >> 1, 1, 1);
    }
    __syncthreads();
    if (kh == 2){                       // S3
      *(f32x4*)ridx(mf2, 0, 0, 0) = acc[0][0];
      *(f32x4*)ridx(mf2, 0, 0, 1) = acc[0][1];
      *(f32x4*)ridx(mf2, 0, 1, 0) = acc[1][0];
      *(f32x4*)ridx(mf2, 0, 1, 1) = acc[1][1];
    }
    __syncthreads();
    if (kh == 0){                       // S4
      acc[0][0] += *(const f32x4*)ridx(mf2, 0, 0, 0);
      acc[0][1] += *(const f32x4*)ridx(mf2, 0, 0, 1);
      acc[1][0] += *(const f32x4*)ridx(mf2, 0, 1, 0);
      acc[1][1] += *(const f32x4*)ridx(mf2, 0, 1, 1);
    }
    __syncthreads();
    if (kh == 0){                       // S5: fin[g][cell]  (cell = n_loc*8+uu)
      #pragma unroll
      for (int m = 0; m < 2; ++m)
        #pragma unroll
        for (int jf = 0; jf < 2; ++jf){
          const int g = jf * 2 + (ra >> 3);
          const int nl = mf2 * 32 + m * 16 + q * 4;
          #pragma unroll
          for (int i = 0; i < 4; ++i)
            redu[g * 512 + (nl + i) * 8 + (ra & 7)] = acc[m][jf][i];
        }
    }
    __syncthreads();

    // ---------- epilogue: 1 thread per (n,u) cell, conflict-free reads ----------
    {
      const float av = redu[tid]        + bf2f(xw0) + b0;
      const float fv = redu[512 + tid]  + bf2f(xw1) + b1;
      const float ov = redu[1024 + tid] + bf2f(xw2) + b2;
      const float gv = redu[1536 + tid] + bf2f(xw3) + b3;
      const float ig = 1.f / (1.f + __expf(-av));
      const float fg = 1.f / (1.f + __expf(-fv));
      const float og = 1.f / (1.f + __expf(-ov));
      const float gcl = fminf(fmaxf(gv, -20.f), 20.f);
      const float e2g = __expf(2.f * gcl);
      const float gg = (e2g - 1.f) / (e2g + 1.f);
      creg = fg * creg + ig * gg;
      const float ccl = fminf(fmaxf(creg, -20.f), 20.f);
      const float e2c = __expf(2.f * ccl);
      const float th = (e2c - 1.f) / (e2c + 1.f);
      const float hn = og * th;
      hWp[(size_t)cn * 1024 + cu] = f2bf(hn);
      __builtin_nontemporal_store(hn, &out[((size_t)cn * 64 + t) * 1024 + cu]);
    }
    if (t < 63) gbar3(flags, go, bid, ++phase);   // barB: h(t+1) visible
  }
}

// ---------------- launch ----------------

extern "C" void kernel_launch(void* const* d_in, const int* in_sizes, int n_in,
                              void* d_out, int out_size, void* d_ws, size_t ws_size,
                              hipStream_t stream)
{
  const float* x     = (const float*)d_in[0];
  const float* A     = (const float*)d_in[1];
  const float* Wx    = (const float*)d_in[2];
  const float* Wh    = (const float*)d_in[3];
  const float* Wattn = (const float*)d_in[4];
  const float* b     = (const float*)d_in[5];
  float* out = (float*)d_out;
  char* ws = (char*)d_ws;

  short*    W3T   = (short*)(ws + 0);             // 25165824
  short*    Abf   = (short*)(ws + 25165824);      //  4194304
  short*    xbf   = (short*)(ws + 29360128);      // 16777216
  short*    hbuf  = (short*)(ws + 46137344);      //   524288 (2 parities)
  short*    abuf  = (short*)(ws + 46661632);      //   262144
  float*    cbuf  = (float*)(ws + 46923776);      //   524288
  short*    xwx   = (short*)(ws + 47448064);      // 67108864 (bf16)
  unsigned* flags = (unsigned*)(ws + 114556928);  //    32768 (flags + go)

  hipLaunchKernelGGL(k_wt,   dim3(48 * 64), dim3(256), 0, stream, Wx, Wh, Wattn, W3T);
  hipLaunchKernelGGL(k_cast, dim3(2097152 / 256), dim3(256), 0, stream, x, xbf, 2097152);
  hipLaunchKernelGGL(k_cast, dim3(524288 / 256),  dim3(256), 0, stream, A, Abf, 524288);
  hipLaunchKernelGGL(k_init, dim3(512), dim3(256), 0, stream, A, cbuf, hbuf, flags);
  hipLaunchKernelGGL(k_xwx,  dim3(2048), dim3(256), 0, stream, xbf, W3T, xwx);
  hipLaunchKernelGGL(k_loop, dim3(256), dim3(512), 0, stream,
                     W3T, Abf, hbuf, abuf, cbuf, xwx, b, out, flags);
}

// Round 8
// 1548.224 us; speedup vs baseline: 2.8151x; 1.4608x over previous
//
#include <hip/hip_runtime.h>
#include <stdint.h>
#include <math.h>

typedef __attribute__((ext_vector_type(8))) short short8;
typedef __attribute__((ext_vector_type(4))) short short4v;
typedef __attribute__((ext_vector_type(4))) float f32x4;

__device__ __forceinline__ short f2bf(float f){
  union { float f; uint32_t u; } x; x.f = f;
  uint32_t r = x.u + 0x7fffu + ((x.u >> 16) & 1u);
  return (short)(r >> 16);
}
__device__ __forceinline__ float bf2f(short s){
  union { uint32_t u; float f; } x; x.u = ((uint32_t)(uint16_t)s) << 16;
  return x.f;
}

// ---- LLC-coherent access helpers: relaxed agent-scope atomics (sc0 sc1).
// Bypass L1/L2; coherence point is the LLC. No cache-wide fences needed.
__device__ __forceinline__ unsigned ld_llc_u32(const void* p){
  return __hip_atomic_load((const unsigned*)p, __ATOMIC_RELAXED, __HIP_MEMORY_SCOPE_AGENT);
}
__device__ __forceinline__ void st_llc_u32(void* p, unsigned v){
  __hip_atomic_store((unsigned*)p, v, __ATOMIC_RELAXED, __HIP_MEMORY_SCOPE_AGENT);
}
__device__ __forceinline__ short8 ld_llc_b128(const void* p){
  unsigned long long a = __hip_atomic_load((const unsigned long long*)p, __ATOMIC_RELAXED, __HIP_MEMORY_SCOPE_AGENT);
  unsigned long long b = __hip_atomic_load(((const unsigned long long*)p) + 1, __ATOMIC_RELAXED, __HIP_MEMORY_SCOPE_AGENT);
  union { unsigned long long q[2]; short8 s; } u;
  u.q[0] = a; u.q[1] = b;
  return u.s;
}

// ---------------- leader grid barrier, fence-free ----------------
// Release: each wave drains its own (LLC-targeted) stores with vmcnt(0),
// block syncs, then lane 0 stores the block flag (relaxed, agent).
// Acquire: consumers' data loads bypass L1/L2 anyway -> nothing to invalidate.
__device__ __forceinline__ void gbar_arrive(unsigned* flags, int bid, unsigned phase){
  asm volatile("s_waitcnt vmcnt(0)" ::: "memory");
  __syncthreads();
  if (threadIdx.x == 0)
    st_llc_u32(&flags[bid * 16], phase);
}
__device__ __forceinline__ void gbar_wait(unsigned* flags, unsigned* go, int bid, unsigned phase){
  const int tid = threadIdx.x;
  if (bid == 0){
    if (tid < 64){
      for (;;){
        unsigned mn = 0xffffffffu;
        #pragma unroll
        for (int i = 0; i < 4; ++i){
          unsigned v = ld_llc_u32(&flags[(tid * 4 + i) * 16]);
          mn = v < mn ? v : mn;
        }
        if (__all(mn >= phase)) break;
        __builtin_amdgcn_s_sleep(2);
      }
      if (tid == 0) st_llc_u32(go, phase);
    }
  } else {
    if (tid == 0){
      while (ld_llc_u32(go) < phase) __builtin_amdgcn_s_sleep(1);
    }
  }
  __syncthreads();
}

// ---------------- prep kernels ----------------

// Transposed, bf16, concatenated weights: W3T[j][k], j in [0,4096), k in [0,3072)
__global__ __launch_bounds__(256) void k_wt(const float* __restrict__ Wx,
                                            const float* __restrict__ Wh,
                                            const float* __restrict__ Wattn,
                                            short* __restrict__ W3T){
  __shared__ float tile[64][65];
  int bk = blockIdx.x % 48, bj = blockIdx.x / 48;
  int tx = threadIdx.x & 63, ty = threadIdx.x >> 6;
  int k0 = bk * 64, j0 = bj * 64;
  #pragma unroll
  for (int i = 0; i < 16; ++i){
    int kk = ty * 16 + i;
    int k = k0 + kk;
    const float* src = (k < 1024) ? (Wx + (size_t)k * 4096)
                     : (k < 2048) ? (Wh + (size_t)(k - 1024) * 4096)
                                  : (Wattn + (size_t)(k - 2048) * 4096);
    tile[kk][tx] = src[j0 + tx];
  }
  __syncthreads();
  #pragma unroll
  for (int i = 0; i < 16; ++i){
    int jj = ty * 16 + i;
    W3T[(size_t)(j0 + jj) * 3072 + k0 + tx] = f2bf(tile[tx][jj]);
  }
}

__global__ __launch_bounds__(256) void k_cast(const float* __restrict__ in,
                                              short* __restrict__ out, int n4){
  int i = blockIdx.x * 256 + threadIdx.x;
  if (i >= n4) return;
  float4 v = ((const float4*)in)[i];
  short4v o; o[0] = f2bf(v.x); o[1] = f2bf(v.y); o[2] = f2bf(v.z); o[3] = f2bf(v.w);
  *(short4v*)(out + (size_t)i * 4) = o;
}

// h0 = c0 = mean over L=16 of A; zero barrier flags + go
__global__ __launch_bounds__(256) void k_init(const float* __restrict__ A,
                                              float* __restrict__ c,
                                              short* __restrict__ hb0,
                                              unsigned* __restrict__ flags){
  int idx = blockIdx.x * 256 + threadIdx.x;    // N*H = 131072
  if (idx < 8192) flags[idx] = 0u;
  const float* p = A + (size_t)idx * 16;
  float s = 0.f;
  #pragma unroll
  for (int l = 0; l < 16; ++l) s += p[l];
  s *= (1.f / 16.f);
  c[idx] = s;
  hb0[idx] = f2bf(s);
}

// ---------------- xwx precompute (128x128 tile GEMM, bf16 out) ----
typedef const __attribute__((address_space(1))) uint32_t* gas1_t;
typedef __attribute__((address_space(3))) uint32_t* las3_t;

__global__ __launch_bounds__(256) void k_xwx(const short* __restrict__ xbf,
                                             const short* __restrict__ W3T,
                                             short* __restrict__ xwx){
  __shared__ short ldsA[128 * 64];
  __shared__ short ldsB[128 * 64];
  const int tid  = threadIdx.x;
  const int lane = tid & 63;
  const int wave = tid >> 6;

  const int orig = blockIdx.x;
  const int wg = (orig & 7) * 256 + (orig >> 3);
  const int n_t = wg >> 6;
  const int m_t = wg & 63;
  const int m0 = m_t * 128;
  const int n0 = n_t * 128;

  const int ra = lane & 15;
  const int q  = lane >> 4;

  f32x4 acc[4][4];
  #pragma unroll
  for (int mf = 0; mf < 4; ++mf)
    #pragma unroll
    for (int jf = 0; jf < 4; ++jf) acc[mf][jf] = f32x4{0.f,0.f,0.f,0.f};

  const int wm = wave >> 1;
  const int wn = wave & 1;

  for (int kt = 0; kt < 16; ++kt){
    const int kb = kt * 64;
    #pragma unroll
    for (int r = 0; r < 4; ++r){
      int id = (wave * 4 + r) * 64 + lane;
      int row = id >> 3, c = id & 7;
      int csrc = c ^ (row & 7);
      const short* src = xbf + (size_t)(m0 + row) * 1024 + kb + csrc * 8;
      short* dst = ldsA + (wave * 4 + r) * 512;
      __builtin_amdgcn_global_load_lds((gas1_t)(const void*)src, (las3_t)(void*)dst, 16, 0, 0);
    }
    #pragma unroll
    for (int r = 0; r < 4; ++r){
      int id = (wave * 4 + r) * 64 + lane;
      int row = id >> 3, c = id & 7;
      int csrc = c ^ (row & 7);
      const short* src = W3T + (size_t)(n0 + row) * 3072 + kb + csrc * 8;
      short* dst = ldsB + (wave * 4 + r) * 512;
      __builtin_amdgcn_global_load_lds((gas1_t)(const void*)src, (las3_t)(void*)dst, 16, 0, 0);
    }
    asm volatile("s_waitcnt vmcnt(0)" ::: "memory");
    __syncthreads();

    #pragma unroll
    for (int kk = 0; kk < 64; kk += 32){
      const int cc = (kk >> 3) + q;
      short8 af[4], bfr[4];
      #pragma unroll
      for (int mf = 0; mf < 4; ++mf){
        int row = wm * 64 + mf * 16 + ra;
        af[mf] = *(const short8*)(ldsA + row * 64 + ((cc ^ (row & 7)) << 3));
      }
      #pragma unroll
      for (int jf = 0; jf < 4; ++jf){
        int row = wn * 64 + jf * 16 + ra;
        bfr[jf] = *(const short8*)(ldsB + row * 64 + ((cc ^ (row & 7)) << 3));
      }
      #pragma unroll
      for (int mf = 0; mf < 4; ++mf)
        #pragma unroll
        for (int jf = 0; jf < 4; ++jf)
          acc[mf][jf] = __builtin_amdgcn_mfma_f32_16x16x32_bf16(af[mf], bfr[jf], acc[mf][jf], 0, 0, 0);
    }
    __syncthreads();
  }

  #pragma unroll
  for (int mf = 0; mf < 4; ++mf)
    #pragma unroll
    for (int jf = 0; jf < 4; ++jf)
      #pragma unroll
      for (int i = 0; i < 4; ++i){
        int row = m0 + wm * 64 + mf * 16 + q * 4 + i;
        int col = n0 + wn * 64 + jf * 16 + ra;
        xwx[(size_t)row * 4096 + col] = f2bf(acc[mf][jf][i]);
      }
}

// ---------------- persistent recurrence kernel ----------------
// 256 blocks x 512 threads, 1 block/CU. Block: mh = bid&1 (64 n), jb = bid>>1
// (u0 = jb*8; 32 j = 4 gates x 8 u). W slice [32j][2048k] in LDS all 64 steps.
// 8 waves = (mf2 = wave&1) x (kh = wave>>1: 512-k quarter).
// Cross-block traffic (h, abuf) via LLC-coherent relaxed atomics; no fences.
__global__ __launch_bounds__(512, 1) void k_loop(
    const short* __restrict__ W3T,
    const short* __restrict__ Abf,     // [128][1024][16] bf16
    short* __restrict__ hbuf,          // [2][128][1024] bf16
    short* __restrict__ abuf,          // [128][1024] bf16
    const float* __restrict__ cbuf,    // [128][1024] f32
    const short* __restrict__ xwx,     // [8192][4096] bf16
    const float* __restrict__ bias,    // [4096] f32
    float* __restrict__ out,           // [128][64][1024] f32
    unsigned* __restrict__ flags)
{
  __shared__ short Wl[65536];          // 128 KB: [j32][kc256] 16B chunks, XOR-swizzled
  __shared__ float redu[4096];         // 16 KB reduce + fin union
  __shared__ float sred[8][16];

  unsigned* go = flags + 4096;

  const int tid  = threadIdx.x;
  const int lane = tid & 63;
  const int wave = tid >> 6;
  const int bid  = blockIdx.x;
  const int mh   = bid & 1;
  const int jb   = bid >> 1;           // 0..127
  const int u0   = jb * 8;
  const int ra   = lane & 15;
  const int q    = lane >> 4;
  const int mf2  = wave & 1;           // row half within block (32 rows)
  const int kh   = wave >> 1;          // K quarter (512)

  // ---- prologue: W slice -> LDS (once). j(jf,rr) = (jf*2+(rr>>3))*1024 + u0 + (rr&7)
  #pragma unroll
  for (int it = 0; it < 16; ++it){
    int c16 = it * 512 + tid;          // 0..8191
    int jl = c16 >> 8;                 // 0..31
    int kc = c16 & 255;
    int jf = jl >> 4, rr = jl & 15;
    int j = (jf * 2 + (rr >> 3)) * 1024 + u0 + (rr & 7);
    short8 v = *(const short8*)(W3T + (size_t)j * 3072 + 1024 + kc * 8);
    int pc = (jf * 16 + rr) * 256 + (kc ^ (rr & 7));
    *(short8*)(Wl + pc * 8) = v;
  }

  // ---- hoisted constants: attention A-fragments (step-invariant!)
  short8 a00{}, a01{}, a10{}, a11{};
  if (bid < 128){
    const short8* ap0 = (const short8*)(Abf + ((size_t)bid * 1024 + tid * 2 + 0) * 16);
    const short8* ap1 = (const short8*)(Abf + ((size_t)bid * 1024 + tid * 2 + 1) * 16);
    a00 = ap0[0]; a01 = ap0[1]; a10 = ap1[0]; a11 = ap1[1];
  }

  // ---- per-thread LSTM cell (n_loc, uu); c and bias in registers for all steps
  const int n_loc = tid >> 3, uu = tid & 7;
  const int cn = mh * 64 + n_loc;
  const int cu = u0 + uu;
  float creg = cbuf[(size_t)cn * 1024 + cu];
  const float b0 = bias[cu], b1 = bias[1024 + cu], b2 = bias[2048 + cu], b3 = bias[3072 + cu];
  __syncthreads();

  unsigned phase = 0;

  for (int t = 0; t < 64; ++t){
    const short* hRp = hbuf + (size_t)(t & 1) * 131072;
    short*       hWp = hbuf + (size_t)((t + 1) & 1) * 131072;

    // ---------- phase A: attention (blocks 0..127, one per n) ----------
    if (bid < 128){
      unsigned hv2 = ld_llc_u32(hRp + bid * 1024 + tid * 2);
      float h0v = bf2f((short)(hv2 & 0xffffu));
      float h1v = bf2f((short)(hv2 >> 16));
      float sc[16];
      #pragma unroll
      for (int l = 0; l < 8; ++l){
        sc[l]     = h0v * bf2f(a00[l]) + h1v * bf2f(a10[l]);
        sc[8 + l] = h0v * bf2f(a01[l]) + h1v * bf2f(a11[l]);
      }
      #pragma unroll
      for (int off = 1; off < 64; off <<= 1)
        #pragma unroll
        for (int l = 0; l < 16; ++l) sc[l] += __shfl_xor(sc[l], off);
      if (lane == 0)
        #pragma unroll
        for (int l = 0; l < 16; ++l) sred[wave][l] = sc[l];
      __syncthreads();
      float s[16], mx = -1e30f, sum = 0.f;
      #pragma unroll
      for (int l = 0; l < 16; ++l){
        float v = sred[0][l];
        #pragma unroll
        for (int w = 1; w < 8; ++w) v += sred[w][l];
        s[l] = v * 0.03125f;
        mx = fmaxf(mx, s[l]);
      }
      #pragma unroll
      for (int l = 0; l < 16; ++l){ s[l] = __expf(s[l] - mx); sum += s[l]; }
      const float inv = 1.f / sum;
      float ac0 = 0.f, ac1 = 0.f;
      #pragma unroll
      for (int l = 0; l < 8; ++l){
        ac0 += s[l] * bf2f(a00[l]) + s[8 + l] * bf2f(a01[l]);
        ac1 += s[l] * bf2f(a10[l]) + s[8 + l] * bf2f(a11[l]);
      }
      unsigned pk = (unsigned)(unsigned short)f2bf(ac0 * inv)
                  | ((unsigned)(unsigned short)f2bf(ac1 * inv) << 16);
      st_llc_u32(abuf + bid * 1024 + tid * 2, pk);
    } else {
      __syncthreads();                 // keep barrier counts identical
    }

    gbar_arrive(flags, bid, ++phase);  // barA arrive: abuf stores at LLC

    // ---------- prefetch under barA wait ----------
    const short* xp = xwx + ((size_t)cn * 64 + t) * 4096;
    const short xw0 = xp[cu], xw1 = xp[1024 + cu], xw2 = xp[2048 + cu], xw3 = xp[3072 + cu];

    auto loadA = [&](int ks, int m) -> short8 {
      const int kk = ks * 32 + q * 8;
      const int row = mh * 64 + mf2 * 32 + m * 16 + ra;
      const short* p = (kh < 2) ? (hRp + row * 1024 + kh * 512 + kk)
                                : (abuf + row * 1024 + (kh - 2) * 512 + kk);
      return ld_llc_b128(p);
    };
    auto loadB = [&](int ks, int jf) -> short8 {
      const int kcg = kh * 64 + ks * 4 + q;
      const int sw = kcg ^ (ra & 7);
      return *(const short8*)(Wl + (((jf * 16 + ra) * 256) + sw) * 8);
    };

    short8 Ab[4][2], Bb[2][2];
    Bb[0][0] = loadB(0, 0); Bb[0][1] = loadB(0, 1);
    Bb[1][0] = loadB(1, 0); Bb[1][1] = loadB(1, 1);
    if (kh < 2){                       // h(t) is stable since barB(t-1): safe pre-wait
      #pragma unroll
      for (int p = 0; p < 4; ++p){ Ab[p][0] = loadA(p, 0); Ab[p][1] = loadA(p, 1); }
    }

    gbar_wait(flags, go, bid, phase);  // barA complete: abuf visible

    if (kh >= 2){
      #pragma unroll
      for (int p = 0; p < 4; ++p){ Ab[p][0] = loadA(p, 0); Ab[p][1] = loadA(p, 1); }
    }

    // ---------- phase B: GEMM, 16 K-iters, A 4-deep / B 2-deep prefetch ----------
    f32x4 acc[2][2];
    acc[0][0] = f32x4{0.f,0.f,0.f,0.f}; acc[0][1] = f32x4{0.f,0.f,0.f,0.f};
    acc[1][0] = f32x4{0.f,0.f,0.f,0.f}; acc[1][1] = f32x4{0.f,0.f,0.f,0.f};

    #pragma unroll
    for (int ks = 0; ks < 16; ++ks){
      short8 av0 = Ab[ks & 3][0], av1 = Ab[ks & 3][1];
      short8 bv0 = Bb[ks & 1][0], bv1 = Bb[ks & 1][1];
      if (ks < 12){ Ab[ks & 3][0] = loadA(ks + 4, 0); Ab[ks & 3][1] = loadA(ks + 4, 1); }
      if (ks < 14){ Bb[ks & 1][0] = loadB(ks + 2, 0); Bb[ks & 1][1] = loadB(ks + 2, 1); }
      acc[0][0] = __builtin_amdgcn_mfma_f32_16x16x32_bf16(av0, bv0, acc[0][0], 0, 0, 0);
      acc[0][1] = __builtin_amdgcn_mfma_f32_16x16x32_bf16(av0, bv1, acc[0][1], 0, 0, 0);
      acc[1][0] = __builtin_amdgcn_mfma_f32_16x16x32_bf16(av1, bv0, acc[1][0], 0, 0, 0);
      acc[1][1] = __builtin_amdgcn_mfma_f32_16x16x32_bf16(av1, bv1, acc[1][1], 0, 0, 0);
    }

    // ---------- reduction over kh (pairs) ----------
    auto ridx = [&](int m2, int khq, int m, int jf) -> float* {
      return &redu[((((m2 * 2 + khq) * 2 + m) * 2 + jf) * 64 + lane) * 4];
    };
    if (kh & 1){                        // S1: kh 1,3 write
      *(f32x4*)ridx(mf2, kh >> 1, 0, 0) = acc[0][0];
      *(f32x4*)ridx(mf2, kh >> 1, 0, 1) = acc[0][1];
      *(f32x4*)ridx(mf2, kh >> 1, 1, 0) = acc[1][0];
      *(f32x4*)ridx(mf2, kh >> 1, 1, 1) = acc[1][1];
    }
    __syncthreads();
    if (!(kh & 1)){                     // S2: kh 0,2 add partner
      acc[0][0] += *(const f32x4*)ridx(mf2, kh >> 1, 0, 0);
      acc[0][1] += *(const f32x4*)ridx(mf2, kh >> 1, 0, 1);
      acc[1][0] += *(const f32x4*)ridx(mf2, kh >> 1, 1, 0);
      acc[1][1] += *(const f32x4*)ridx(mf2, kh >> 1, 1, 1);
    }
    __syncthreads();
    if (kh == 2){                       // S3
      *(f32x4*)ridx(mf2, 0, 0, 0) = acc[0][0];
      *(f32x4*)ridx(mf2, 0, 0, 1) = acc[0][1];
      *(f32x4*)ridx(mf2, 0, 1, 0) = acc[1][0];
      *(f32x4*)ridx(mf2, 0, 1, 1) = acc[1][1];
    }
    __syncthreads();
    if (kh == 0){                       // S4
      acc[0][0] += *(const f32x4*)ridx(mf2, 0, 0, 0);
      acc[0][1] += *(const f32x4*)ridx(mf2, 0, 0, 1);
      acc[1][0] += *(const f32x4*)ridx(mf2, 0, 1, 0);
      acc[1][1] += *(const f32x4*)ridx(mf2, 0, 1, 1);
    }
    __syncthreads();
    if (kh == 0){                       // S5: fin[g][cell]  (cell = n_loc*8+uu)
      #pragma unroll
      for (int m = 0; m < 2; ++m)
        #pragma unroll
        for (int jf = 0; jf < 2; ++jf){
          const int g = jf * 2 + (ra >> 3);
          const int nl = mf2 * 32 + m * 16 + q * 4;
          #pragma unroll
          for (int i = 0; i < 4; ++i)
            redu[g * 512 + (nl + i) * 8 + (ra & 7)] = acc[m][jf][i];
        }
    }
    __syncthreads();

    // ---------- epilogue: 1 thread per (n,u) cell ----------
    {
      const float av = redu[tid]        + bf2f(xw0) + b0;
      const float fv = redu[512 + tid]  + bf2f(xw1) + b1;
      const float ov = redu[1024 + tid] + bf2f(xw2) + b2;
      const float gv = redu[1536 + tid] + bf2f(xw3) + b3;
      const float ig = 1.f / (1.f + __expf(-av));
      const float fg = 1.f / (1.f + __expf(-fv));
      const float og = 1.f / (1.f + __expf(-ov));
      const float gcl = fminf(fmaxf(gv, -20.f), 20.f);
      const float e2g = __expf(2.f * gcl);
      const float gg = (e2g - 1.f) / (e2g + 1.f);
      creg = fg * creg + ig * gg;
      const float ccl = fminf(fmaxf(creg, -20.f), 20.f);
      const float e2c = __expf(2.f * ccl);
      const float th = (e2c - 1.f) / (e2c + 1.f);
      const float hn = og * th;
      const float hn2 = __shfl_xor(hn, 1);
      if ((tid & 1) == 0){
        unsigned pk = (unsigned)(unsigned short)f2bf(hn)
                    | ((unsigned)(unsigned short)f2bf(hn2) << 16);
        st_llc_u32(hWp + (size_t)cn * 1024 + cu, pk);   // cu is even here
      }
      if (t < 63){
        gbar_arrive(flags, bid, ++phase);               // barB arrive: hW at LLC
        __builtin_nontemporal_store(hn, &out[((size_t)cn * 64 + t) * 1024 + cu]);
        gbar_wait(flags, go, bid, phase);               // barB complete
      } else {
        __builtin_nontemporal_store(hn, &out[((size_t)cn * 64 + t) * 1024 + cu]);
      }
    }
  }
}

// ---------------- launch ----------------

extern "C" void kernel_launch(void* const* d_in, const int* in_sizes, int n_in,
                              void* d_out, int out_size, void* d_ws, size_t ws_size,
                              hipStream_t stream)
{
  const float* x     = (const float*)d_in[0];
  const float* A     = (const float*)d_in[1];
  const float* Wx    = (const float*)d_in[2];
  const float* Wh    = (const float*)d_in[3];
  const float* Wattn = (const float*)d_in[4];
  const float* b     = (const float*)d_in[5];
  float* out = (float*)d_out;
  char* ws = (char*)d_ws;

  short*    W3T   = (short*)(ws + 0);             // 25165824
  short*    Abf   = (short*)(ws + 25165824);      //  4194304
  short*    xbf   = (short*)(ws + 29360128);      // 16777216
  short*    hbuf  = (short*)(ws + 46137344);      //   524288 (2 parities)
  short*    abuf  = (short*)(ws + 46661632);      //   262144
  float*    cbuf  = (float*)(ws + 46923776);      //   524288
  short*    xwx   = (short*)(ws + 47448064);      // 67108864 (bf16)
  unsigned* flags = (unsigned*)(ws + 114556928);  //    32768 (flags + go)

  hipLaunchKernelGGL(k_wt,   dim3(48 * 64), dim3(256), 0, stream, Wx, Wh, Wattn, W3T);
  hipLaunchKernelGGL(k_cast, dim3(2097152 / 256), dim3(256), 0, stream, x, xbf, 2097152);
  hipLaunchKernelGGL(k_cast, dim3(524288 / 256),  dim3(256), 0, stream, A, Abf, 524288);
  hipLaunchKernelGGL(k_init, dim3(512), dim3(256), 0, stream, A, cbuf, hbuf, flags);
  hipLaunchKernelGGL(k_xwx,  dim3(2048), dim3(256), 0, stream, xbf, W3T, xwx);
  hipLaunchKernelGGL(k_loop, dim3(256), dim3(512), 0, stream,
                     W3T, Abf, hbuf, abuf, cbuf, xwx, b, out, flags);
}

// Round 9
// 1063.447 us; speedup vs baseline: 4.0984x; 1.4559x over previous
//
#include <hip/hip_runtime.h>
#include <stdint.h>
#include <math.h>

typedef __attribute__((ext_vector_type(8))) short short8;
typedef __attribute__((ext_vector_type(4))) short short4v;
typedef __attribute__((ext_vector_type(4))) float f32x4;

__device__ __forceinline__ short f2bf(float f){
  union { float f; uint32_t u; } x; x.f = f;
  uint32_t r = x.u + 0x7fffu + ((x.u >> 16) & 1u);
  return (short)(r >> 16);
}
__device__ __forceinline__ float bf2f(short s){
  union { uint32_t u; float f; } x; x.u = ((uint32_t)(uint16_t)s) << 16;
  return x.f;
}

// ---- LLC-coherent store/load (relaxed agent-scope atomics; bypass L1/L2).
// Producers use these so data reaches the coherence point before the flag.
__device__ __forceinline__ unsigned ld_llc_u32(const void* p){
  return __hip_atomic_load((const unsigned*)p, __ATOMIC_RELAXED, __HIP_MEMORY_SCOPE_AGENT);
}
__device__ __forceinline__ void st_llc_u32(void* p, unsigned v){
  __hip_atomic_store((unsigned*)p, v, __ATOMIC_RELAXED, __HIP_MEMORY_SCOPE_AGENT);
}

// ---------------- leader grid barrier, fence-free ----------------
// Consumers read rotated (never-before-touched) addresses -> normal cached
// loads are safe; no cache maintenance anywhere.
__device__ __forceinline__ void gbar_arrive(unsigned* flags, int bid, unsigned phase){
  asm volatile("s_waitcnt vmcnt(0)" ::: "memory");
  __syncthreads();
  if (threadIdx.x == 0)
    st_llc_u32(&flags[bid * 16], phase);
}
__device__ __forceinline__ void gbar_wait(unsigned* flags, unsigned* go, int bid, unsigned phase){
  const int tid = threadIdx.x;
  if (bid == 0){
    if (tid < 64){
      for (;;){
        unsigned mn = 0xffffffffu;
        #pragma unroll
        for (int i = 0; i < 4; ++i){
          unsigned v = ld_llc_u32(&flags[(tid * 4 + i) * 16]);
          mn = v < mn ? v : mn;
        }
        if (__all(mn >= phase)) break;
        __builtin_amdgcn_s_sleep(2);
      }
      if (tid == 0) st_llc_u32(go, phase);
    }
  } else {
    if (tid == 0){
      while (ld_llc_u32(go) < phase) __builtin_amdgcn_s_sleep(1);
    }
  }
  __syncthreads();
}

// ---------------- prep kernels ----------------

// Transposed, bf16, concatenated weights: W3T[j][k], j in [0,4096), k in [0,3072)
__global__ __launch_bounds__(256) void k_wt(const float* __restrict__ Wx,
                                            const float* __restrict__ Wh,
                                            const float* __restrict__ Wattn,
                                            short* __restrict__ W3T){
  __shared__ float tile[64][65];
  int bk = blockIdx.x % 48, bj = blockIdx.x / 48;
  int tx = threadIdx.x & 63, ty = threadIdx.x >> 6;
  int k0 = bk * 64, j0 = bj * 64;
  #pragma unroll
  for (int i = 0; i < 16; ++i){
    int kk = ty * 16 + i;
    int k = k0 + kk;
    const float* src = (k < 1024) ? (Wx + (size_t)k * 4096)
                     : (k < 2048) ? (Wh + (size_t)(k - 1024) * 4096)
                                  : (Wattn + (size_t)(k - 2048) * 4096);
    tile[kk][tx] = src[j0 + tx];
  }
  __syncthreads();
  #pragma unroll
  for (int i = 0; i < 16; ++i){
    int jj = ty * 16 + i;
    W3T[(size_t)(j0 + jj) * 3072 + k0 + tx] = f2bf(tile[tx][jj]);
  }
}

__global__ __launch_bounds__(256) void k_cast(const float* __restrict__ in,
                                              short* __restrict__ out, int n4){
  int i = blockIdx.x * 256 + threadIdx.x;
  if (i >= n4) return;
  float4 v = ((const float4*)in)[i];
  short4v o; o[0] = f2bf(v.x); o[1] = f2bf(v.y); o[2] = f2bf(v.z); o[3] = f2bf(v.w);
  *(short4v*)(out + (size_t)i * 4) = o;
}

// h0 = c0 = mean over L=16 of A; h0 -> hbuf slot 0; zero barrier flags + go
__global__ __launch_bounds__(256) void k_init(const float* __restrict__ A,
                                              float* __restrict__ c,
                                              short* __restrict__ hb0,
                                              unsigned* __restrict__ flags){
  int idx = blockIdx.x * 256 + threadIdx.x;    // N*H = 131072
  if (idx < 8192) flags[idx] = 0u;
  const float* p = A + (size_t)idx * 16;
  float s = 0.f;
  #pragma unroll
  for (int l = 0; l < 16; ++l) s += p[l];
  s *= (1.f / 16.f);
  c[idx] = s;
  hb0[idx] = f2bf(s);
}

// ---------------- xwx precompute (128x128 tile GEMM, bf16 out) ----
typedef const __attribute__((address_space(1))) uint32_t* gas1_t;
typedef __attribute__((address_space(3))) uint32_t* las3_t;

__global__ __launch_bounds__(256) void k_xwx(const short* __restrict__ xbf,
                                             const short* __restrict__ W3T,
                                             short* __restrict__ xwx){
  __shared__ short ldsA[128 * 64];
  __shared__ short ldsB[128 * 64];
  const int tid  = threadIdx.x;
  const int lane = tid & 63;
  const int wave = tid >> 6;

  const int orig = blockIdx.x;
  const int wg = (orig & 7) * 256 + (orig >> 3);
  const int n_t = wg >> 6;
  const int m_t = wg & 63;
  const int m0 = m_t * 128;
  const int n0 = n_t * 128;

  const int ra = lane & 15;
  const int q  = lane >> 4;

  f32x4 acc[4][4];
  #pragma unroll
  for (int mf = 0; mf < 4; ++mf)
    #pragma unroll
    for (int jf = 0; jf < 4; ++jf) acc[mf][jf] = f32x4{0.f,0.f,0.f,0.f};

  const int wm = wave >> 1;
  const int wn = wave & 1;

  for (int kt = 0; kt < 16; ++kt){
    const int kb = kt * 64;
    #pragma unroll
    for (int r = 0; r < 4; ++r){
      int id = (wave * 4 + r) * 64 + lane;
      int row = id >> 3, c = id & 7;
      int csrc = c ^ (row & 7);
      const short* src = xbf + (size_t)(m0 + row) * 1024 + kb + csrc * 8;
      short* dst = ldsA + (wave * 4 + r) * 512;
      __builtin_amdgcn_global_load_lds((gas1_t)(const void*)src, (las3_t)(void*)dst, 16, 0, 0);
    }
    #pragma unroll
    for (int r = 0; r < 4; ++r){
      int id = (wave * 4 + r) * 64 + lane;
      int row = id >> 3, c = id & 7;
      int csrc = c ^ (row & 7);
      const short* src = W3T + (size_t)(n0 + row) * 3072 + kb + csrc * 8;
      short* dst = ldsB + (wave * 4 + r) * 512;
      __builtin_amdgcn_global_load_lds((gas1_t)(const void*)src, (las3_t)(void*)dst, 16, 0, 0);
    }
    asm volatile("s_waitcnt vmcnt(0)" ::: "memory");
    __syncthreads();

    #pragma unroll
    for (int kk = 0; kk < 64; kk += 32){
      const int cc = (kk >> 3) + q;
      short8 af[4], bfr[4];
      #pragma unroll
      for (int mf = 0; mf < 4; ++mf){
        int row = wm * 64 + mf * 16 + ra;
        af[mf] = *(const short8*)(ldsA + row * 64 + ((cc ^ (row & 7)) << 3));
      }
      #pragma unroll
      for (int jf = 0; jf < 4; ++jf){
        int row = wn * 64 + jf * 16 + ra;
        bfr[jf] = *(const short8*)(ldsB + row * 64 + ((cc ^ (row & 7)) << 3));
      }
      #pragma unroll
      for (int mf = 0; mf < 4; ++mf)
        #pragma unroll
        for (int jf = 0; jf < 4; ++jf)
          acc[mf][jf] = __builtin_amdgcn_mfma_f32_16x16x32_bf16(af[mf], bfr[jf], acc[mf][jf], 0, 0, 0);
    }
    __syncthreads();
  }

  #pragma unroll
  for (int mf = 0; mf < 4; ++mf)
    #pragma unroll
    for (int jf = 0; jf < 4; ++jf)
      #pragma unroll
      for (int i = 0; i < 4; ++i){
        int row = m0 + wm * 64 + mf * 16 + q * 4 + i;
        int col = n0 + wn * 64 + jf * 16 + ra;
        xwx[(size_t)row * 4096 + col] = f2bf(acc[mf][jf][i]);
      }
}

// ---------------- persistent recurrence kernel ----------------
// 256 blocks x 512 threads, 1 block/CU. Block: mh = bid&1 (64 n), jb = bid>>1
// (u0 = jb*8; 32 j = 4 gates x 8 u). W slice [32j][2048k] in LDS all 64 steps.
// 8 waves = (mf2 = wave&1) x (kh = wave>>1: 512-k quarter).
// h/abuf ROTATE per step: producers store via LLC; consumers use normal cached
// loads (fresh addresses each step -> no stale-L2 hazard; mh==xcd&1 so all 32
// blocks of an XCD share the h-half -> L2 amortizes the LLC fetch).
__global__ __launch_bounds__(512, 1) void k_loop(
    const short* __restrict__ W3T,
    const short* __restrict__ Abf,     // [128][1024][16] bf16
    short* __restrict__ hbuf,          // [65][128][1024] bf16 (rotating)
    short* __restrict__ abuf,          // [64][128][1024] bf16 (rotating)
    const float* __restrict__ cbuf,    // [128][1024] f32
    const short* __restrict__ xwx,     // [8192][4096] bf16
    const float* __restrict__ bias,    // [4096] f32
    float* __restrict__ out,           // [128][64][1024] f32
    unsigned* __restrict__ flags)
{
  __shared__ short Wl[65536];          // 128 KB: [j32][kc256] 16B chunks, XOR-swizzled
  __shared__ float redu[4096];         // 16 KB reduce + fin union
  __shared__ float sred[8][16];

  unsigned* go = flags + 4096;

  const int tid  = threadIdx.x;
  const int lane = tid & 63;
  const int wave = tid >> 6;
  const int bid  = blockIdx.x;
  const int mh   = bid & 1;
  const int jb   = bid >> 1;           // 0..127
  const int u0   = jb * 8;
  const int ra   = lane & 15;
  const int q    = lane >> 4;
  const int mf2  = wave & 1;           // row half within block (32 rows)
  const int kh   = wave >> 1;          // K quarter (512)

  // ---- prologue: W slice -> LDS (once). j(jf,rr) = (jf*2+(rr>>3))*1024 + u0 + (rr&7)
  #pragma unroll
  for (int it = 0; it < 16; ++it){
    int c16 = it * 512 + tid;          // 0..8191
    int jl = c16 >> 8;                 // 0..31
    int kc = c16 & 255;
    int jf = jl >> 4, rr = jl & 15;
    int j = (jf * 2 + (rr >> 3)) * 1024 + u0 + (rr & 7);
    short8 v = *(const short8*)(W3T + (size_t)j * 3072 + 1024 + kc * 8);
    int pc = (jf * 16 + rr) * 256 + (kc ^ (rr & 7));
    *(short8*)(Wl + pc * 8) = v;
  }

  // ---- hoisted constants: attention A-fragments (step-invariant!)
  short8 a00{}, a01{}, a10{}, a11{};
  if (bid < 128){
    const short8* ap0 = (const short8*)(Abf + ((size_t)bid * 1024 + tid * 2 + 0) * 16);
    const short8* ap1 = (const short8*)(Abf + ((size_t)bid * 1024 + tid * 2 + 1) * 16);
    a00 = ap0[0]; a01 = ap0[1]; a10 = ap1[0]; a11 = ap1[1];
  }

  // ---- per-thread LSTM cell (n_loc, uu); c and bias in registers for all steps
  const int n_loc = tid >> 3, uu = tid & 7;
  const int cn = mh * 64 + n_loc;
  const int cu = u0 + uu;
  float creg = cbuf[(size_t)cn * 1024 + cu];
  const float b0 = bias[cu], b1 = bias[1024 + cu], b2 = bias[2048 + cu], b3 = bias[3072 + cu];
  __syncthreads();

  unsigned phase = 0;

  for (int t = 0; t < 64; ++t){
    const short* hRp = hbuf + (size_t)t * 131072;        // slot t (fresh addr)
    short*       hWp = hbuf + (size_t)(t + 1) * 131072;  // slot t+1
    short*       aT  = abuf + (size_t)t * 131072;        // abuf slot t

    // ---------- phase A: attention (blocks 0..127, one per n) ----------
    if (bid < 128){
      unsigned hv2 = *(const unsigned*)(hRp + bid * 1024 + tid * 2);  // cached load
      float h0v = bf2f((short)(hv2 & 0xffffu));
      float h1v = bf2f((short)(hv2 >> 16));
      float sc[16];
      #pragma unroll
      for (int l = 0; l < 8; ++l){
        sc[l]     = h0v * bf2f(a00[l]) + h1v * bf2f(a10[l]);
        sc[8 + l] = h0v * bf2f(a01[l]) + h1v * bf2f(a11[l]);
      }
      #pragma unroll
      for (int off = 1; off < 64; off <<= 1)
        #pragma unroll
        for (int l = 0; l < 16; ++l) sc[l] += __shfl_xor(sc[l], off);
      if (lane == 0)
        #pragma unroll
        for (int l = 0; l < 16; ++l) sred[wave][l] = sc[l];
      __syncthreads();
      float s[16], mx = -1e30f, sum = 0.f;
      #pragma unroll
      for (int l = 0; l < 16; ++l){
        float v = sred[0][l];
        #pragma unroll
        for (int w = 1; w < 8; ++w) v += sred[w][l];
        s[l] = v * 0.03125f;
        mx = fmaxf(mx, s[l]);
      }
      #pragma unroll
      for (int l = 0; l < 16; ++l){ s[l] = __expf(s[l] - mx); sum += s[l]; }
      const float inv = 1.f / sum;
      float ac0 = 0.f, ac1 = 0.f;
      #pragma unroll
      for (int l = 0; l < 8; ++l){
        ac0 += s[l] * bf2f(a00[l]) + s[8 + l] * bf2f(a01[l]);
        ac1 += s[l] * bf2f(a10[l]) + s[8 + l] * bf2f(a11[l]);
      }
      unsigned pk = (unsigned)(unsigned short)f2bf(ac0 * inv)
                  | ((unsigned)(unsigned short)f2bf(ac1 * inv) << 16);
      st_llc_u32(aT + bid * 1024 + tid * 2, pk);
    } else {
      __syncthreads();                 // keep barrier counts identical
    }

    gbar_arrive(flags, bid, ++phase);  // barA arrive: abuf stores at LLC

    // ---------- prefetch under barA wait (all normal cached loads) ----------
    const short* xp = xwx + ((size_t)cn * 64 + t) * 4096;
    const short xw0 = xp[cu], xw1 = xp[1024 + cu], xw2 = xp[2048 + cu], xw3 = xp[3072 + cu];

    auto loadA = [&](int ks, int m) -> short8 {
      const int kk = ks * 32 + q * 8;
      const int row = mh * 64 + mf2 * 32 + m * 16 + ra;
      const short* p = (kh < 2) ? (hRp + row * 1024 + kh * 512 + kk)
                                : (aT + row * 1024 + (kh - 2) * 512 + kk);
      return *(const short8*)p;
    };
    auto loadB = [&](int ks, int jf) -> short8 {
      const int kcg = kh * 64 + ks * 4 + q;
      const int sw = kcg ^ (ra & 7);
      return *(const short8*)(Wl + (((jf * 16 + ra) * 256) + sw) * 8);
    };

    short8 Ab[4][2], Bb[2][2];
    Bb[0][0] = loadB(0, 0); Bb[0][1] = loadB(0, 1);
    Bb[1][0] = loadB(1, 0); Bb[1][1] = loadB(1, 1);
    if (kh < 2){                       // h(t) stable since barB(t-1): safe pre-wait
      #pragma unroll
      for (int p = 0; p < 4; ++p){ Ab[p][0] = loadA(p, 0); Ab[p][1] = loadA(p, 1); }
    }

    gbar_wait(flags, go, bid, phase);  // barA complete: abuf visible

    if (kh >= 2){
      #pragma unroll
      for (int p = 0; p < 4; ++p){ Ab[p][0] = loadA(p, 0); Ab[p][1] = loadA(p, 1); }
    }

    // ---------- phase B: GEMM, 16 K-iters, A 4-deep / B 2-deep prefetch ----------
    f32x4 acc[2][2];
    acc[0][0] = f32x4{0.f,0.f,0.f,0.f}; acc[0][1] = f32x4{0.f,0.f,0.f,0.f};
    acc[1][0] = f32x4{0.f,0.f,0.f,0.f}; acc[1][1] = f32x4{0.f,0.f,0.f,0.f};

    #pragma unroll
    for (int ks = 0; ks < 16; ++ks){
      short8 av0 = Ab[ks & 3][0], av1 = Ab[ks & 3][1];
      short8 bv0 = Bb[ks & 1][0], bv1 = Bb[ks & 1][1];
      if (ks < 12){ Ab[ks & 3][0] = loadA(ks + 4, 0); Ab[ks & 3][1] = loadA(ks + 4, 1); }
      if (ks < 14){ Bb[ks & 1][0] = loadB(ks + 2, 0); Bb[ks & 1][1] = loadB(ks + 2, 1); }
      acc[0][0] = __builtin_amdgcn_mfma_f32_16x16x32_bf16(av0, bv0, acc[0][0], 0, 0, 0);
      acc[0][1] = __builtin_amdgcn_mfma_f32_16x16x32_bf16(av0, bv1, acc[0][1], 0, 0, 0);
      acc[1][0] = __builtin_amdgcn_mfma_f32_16x16x32_bf16(av1, bv0, acc[1][0], 0, 0, 0);
      acc[1][1] = __builtin_amdgcn_mfma_f32_16x16x32_bf16(av1, bv1, acc[1][1], 0, 0, 0);
    }

    // ---------- reduction over kh (pairs) ----------
    auto ridx = [&](int m2, int khq, int m, int jf) -> float* {
      return &redu[((((m2 * 2 + khq) * 2 + m) * 2 + jf) * 64 + lane) * 4];
    };
    if (kh & 1){                        // S1: kh 1,3 write
      *(f32x4*)ridx(mf2, kh >> 1, 0, 0) = acc[0][0];
      *(f32x4*)ridx(mf2, kh >> 1, 0, 1) = acc[0][1];
      *(f32x4*)ridx(mf2, kh >> 1, 1, 0) = acc[1][0];
      *(f32x4*)ridx(mf2, kh >> 1, 1, 1) = acc[1][1];
    }
    __syncthreads();
    if (!(kh & 1)){                     // S2: kh 0,2 add partner
      acc[0][0] += *(const f32x4*)ridx(mf2, kh >> 1, 0, 0);
      acc[0][1] += *(const f32x4*)ridx(mf2, kh >> 1, 0, 1);
      acc[1][0] += *(const f32x4*)ridx(mf2, kh >> 1, 1, 0);
      acc[1][1] += *(const f32x4*)ridx(mf2, kh >> 1, 1, 1);
    }
    __syncthreads();
    if (kh == 2){                       // S3
      *(f32x4*)ridx(mf2, 0, 0, 0) = acc[0][0];
      *(f32x4*)ridx(mf2, 0, 0, 1) = acc[0][1];
      *(f32x4*)ridx(mf2, 0, 1, 0) = acc[1][0];
      *(f32x4*)ridx(mf2, 0, 1, 1) = acc[1][1];
    }
    __syncthreads();
    if (kh == 0){                       // S4
      acc[0][0] += *(const f32x4*)ridx(mf2, 0, 0, 0);
      acc[0][1] += *(const f32x4*)ridx(mf2, 0, 0, 1);
      acc[1][0] += *(const f32x4*)ridx(mf2, 0, 1, 0);
      acc[1][1] += *(const f32x4*)ridx(mf2, 0, 1, 1);
    }
    __syncthreads();
    if (kh == 0){                       // S5: fin[g][cell]  (cell = n_loc*8+uu)
      #pragma unroll
      for (int m = 0; m < 2; ++m)
        #pragma unroll
        for (int jf = 0; jf < 2; ++jf){
          const int g = jf * 2 + (ra >> 3);
          const int nl = mf2 * 32 + m * 16 + q * 4;
          #pragma unroll
          for (int i = 0; i < 4; ++i)
            redu[g * 512 + (nl + i) * 8 + (ra & 7)] = acc[m][jf][i];
        }
    }
    __syncthreads();

    // ---------- epilogue: 1 thread per (n,u) cell ----------
    {
      const float av = redu[tid]        + bf2f(xw0) + b0;
      const float fv = redu[512 + tid]  + bf2f(xw1) + b1;
      const float ov = redu[1024 + tid] + bf2f(xw2) + b2;
      const float gv = redu[1536 + tid] + bf2f(xw3) + b3;
      const float ig = 1.f / (1.f + __expf(-av));
      const float fg = 1.f / (1.f + __expf(-fv));
      const float og = 1.f / (1.f + __expf(-ov));
      const float gcl = fminf(fmaxf(gv, -20.f), 20.f);
      const float e2g = __expf(2.f * gcl);
      const float gg = (e2g - 1.f) / (e2g + 1.f);
      creg = fg * creg + ig * gg;
      const float ccl = fminf(fmaxf(creg, -20.f), 20.f);
      const float e2c = __expf(2.f * ccl);
      const float th = (e2c - 1.f) / (e2c + 1.f);
      const float hn = og * th;
      const float hn2 = __shfl_xor(hn, 1);
      if ((tid & 1) == 0){
        unsigned pk = (unsigned)(unsigned short)f2bf(hn)
                    | ((unsigned)(unsigned short)f2bf(hn2) << 16);
        st_llc_u32(hWp + (size_t)cn * 1024 + cu, pk);   // cu even here
      }
      if (t < 63){
        gbar_arrive(flags, bid, ++phase);               // barB arrive: hW at LLC
        __builtin_nontemporal_store(hn, &out[((size_t)cn * 64 + t) * 1024 + cu]);
        gbar_wait(flags, go, bid, phase);               // barB complete
      } else {
        __builtin_nontemporal_store(hn, &out[((size_t)cn * 64 + t) * 1024 + cu]);
      }
    }
  }
}

// ---------------- launch ----------------

extern "C" void kernel_launch(void* const* d_in, const int* in_sizes, int n_in,
                              void* d_out, int out_size, void* d_ws, size_t ws_size,
                              hipStream_t stream)
{
  const float* x     = (const float*)d_in[0];
  const float* A     = (const float*)d_in[1];
  const float* Wx    = (const float*)d_in[2];
  const float* Wh    = (const float*)d_in[3];
  const float* Wattn = (const float*)d_in[4];
  const float* b     = (const float*)d_in[5];
  float* out = (float*)d_out;
  char* ws = (char*)d_ws;

  short*    W3T   = (short*)(ws + 0);             // 25165824
  short*    Abf   = (short*)(ws + 25165824);      //  4194304
  short*    xbf   = (short*)(ws + 29360128);      // 16777216
  short*    xwx   = (short*)(ws + 46137344);      // 67108864 (bf16)
  short*    hbuf  = (short*)(ws + 113246208);     // 65 slots x 262144 = 17039360
  short*    abuf  = (short*)(ws + 130285568);     // 64 slots x 262144 = 16777216
  float*    cbuf  = (float*)(ws + 147062784);     //   524288
  unsigned* flags = (unsigned*)(ws + 147587072);  //    32768 (flags + go)

  hipLaunchKernelGGL(k_wt,   dim3(48 * 64), dim3(256), 0, stream, Wx, Wh, Wattn, W3T);
  hipLaunchKernelGGL(k_cast, dim3(2097152 / 256), dim3(256), 0, stream, x, xbf, 2097152);
  hipLaunchKernelGGL(k_cast, dim3(524288 / 256),  dim3(256), 0, stream, A, Abf, 524288);
  hipLaunchKernelGGL(k_init, dim3(512), dim3(256), 0, stream, A, cbuf, hbuf, flags);
  hipLaunchKernelGGL(k_xwx,  dim3(2048), dim3(256), 0, stream, xbf, W3T, xwx);
  hipLaunchKernelGGL(k_loop, dim3(256), dim3(512), 0, stream,
                     W3T, Abf, hbuf, abuf, cbuf, xwx, b, out, flags);
}

// Round 10
// 936.442 us; speedup vs baseline: 4.6543x; 1.1356x over previous
//
#include <hip/hip_runtime.h>
#include <stdint.h>
#include <math.h>

typedef __attribute__((ext_vector_type(8))) short short8;
typedef __attribute__((ext_vector_type(4))) short short4v;
typedef __attribute__((ext_vector_type(4))) float f32x4;

__device__ __forceinline__ short f2bf(float f){
  union { float f; uint32_t u; } x; x.f = f;
  uint32_t r = x.u + 0x7fffu + ((x.u >> 16) & 1u);
  return (short)(r >> 16);
}
__device__ __forceinline__ float bf2f(short s){
  union { uint32_t u; float f; } x; x.u = ((uint32_t)(uint16_t)s) << 16;
  return x.f;
}

__device__ __forceinline__ unsigned ld_llc_u32(const void* p){
  return __hip_atomic_load((const unsigned*)p, __ATOMIC_RELAXED, __HIP_MEMORY_SCOPE_AGENT);
}
__device__ __forceinline__ void st_llc_u32(void* p, unsigned v){
  __hip_atomic_store((unsigned*)p, v, __ATOMIC_RELAXED, __HIP_MEMORY_SCOPE_AGENT);
}

// ---------------- prep kernels (unchanged from R9) ----------------

__global__ __launch_bounds__(256) void k_wt(const float* __restrict__ Wx,
                                            const float* __restrict__ Wh,
                                            const float* __restrict__ Wattn,
                                            short* __restrict__ W3T){
  __shared__ float tile[64][65];
  int bk = blockIdx.x % 48, bj = blockIdx.x / 48;
  int tx = threadIdx.x & 63, ty = threadIdx.x >> 6;
  int k0 = bk * 64, j0 = bj * 64;
  #pragma unroll
  for (int i = 0; i < 16; ++i){
    int kk = ty * 16 + i;
    int k = k0 + kk;
    const float* src = (k < 1024) ? (Wx + (size_t)k * 4096)
                     : (k < 2048) ? (Wh + (size_t)(k - 1024) * 4096)
                                  : (Wattn + (size_t)(k - 2048) * 4096);
    tile[kk][tx] = src[j0 + tx];
  }
  __syncthreads();
  #pragma unroll
  for (int i = 0; i < 16; ++i){
    int jj = ty * 16 + i;
    W3T[(size_t)(j0 + jj) * 3072 + k0 + tx] = f2bf(tile[tx][jj]);
  }
}

__global__ __launch_bounds__(256) void k_cast(const float* __restrict__ in,
                                              short* __restrict__ out, int n4){
  int i = blockIdx.x * 256 + threadIdx.x;
  if (i >= n4) return;
  float4 v = ((const float4*)in)[i];
  short4v o; o[0] = f2bf(v.x); o[1] = f2bf(v.y); o[2] = f2bf(v.z); o[3] = f2bf(v.w);
  *(short4v*)(out + (size_t)i * 4) = o;
}

__global__ __launch_bounds__(256) void k_init(const float* __restrict__ A,
                                              float* __restrict__ c,
                                              short* __restrict__ hb0,
                                              unsigned* __restrict__ flags){
  int idx = blockIdx.x * 256 + threadIdx.x;    // N*H = 131072
  if (idx < 8192) flags[idx] = 0u;
  const float* p = A + (size_t)idx * 16;
  float s = 0.f;
  #pragma unroll
  for (int l = 0; l < 16; ++l) s += p[l];
  s *= (1.f / 16.f);
  c[idx] = s;
  hb0[idx] = f2bf(s);
}

typedef const __attribute__((address_space(1))) uint32_t* gas1_t;
typedef __attribute__((address_space(3))) uint32_t* las3_t;

__global__ __launch_bounds__(256) void k_xwx(const short* __restrict__ xbf,
                                             const short* __restrict__ W3T,
                                             short* __restrict__ xwx){
  __shared__ short ldsA[128 * 64];
  __shared__ short ldsB[128 * 64];
  const int tid  = threadIdx.x;
  const int lane = tid & 63;
  const int wave = tid >> 6;

  const int orig = blockIdx.x;
  const int wg = (orig & 7) * 256 + (orig >> 3);
  const int n_t = wg >> 6;
  const int m_t = wg & 63;
  const int m0 = m_t * 128;
  const int n0 = n_t * 128;

  const int ra = lane & 15;
  const int q  = lane >> 4;

  f32x4 acc[4][4];
  #pragma unroll
  for (int mf = 0; mf < 4; ++mf)
    #pragma unroll
    for (int jf = 0; jf < 4; ++jf) acc[mf][jf] = f32x4{0.f,0.f,0.f,0.f};

  const int wm = wave >> 1;
  const int wn = wave & 1;

  for (int kt = 0; kt < 16; ++kt){
    const int kb = kt * 64;
    #pragma unroll
    for (int r = 0; r < 4; ++r){
      int id = (wave * 4 + r) * 64 + lane;
      int row = id >> 3, c = id & 7;
      int csrc = c ^ (row & 7);
      const short* src = xbf + (size_t)(m0 + row) * 1024 + kb + csrc * 8;
      short* dst = ldsA + (wave * 4 + r) * 512;
      __builtin_amdgcn_global_load_lds((gas1_t)(const void*)src, (las3_t)(void*)dst, 16, 0, 0);
    }
    #pragma unroll
    for (int r = 0; r < 4; ++r){
      int id = (wave * 4 + r) * 64 + lane;
      int row = id >> 3, c = id & 7;
      int csrc = c ^ (row & 7);
      const short* src = W3T + (size_t)(n0 + row) * 3072 + kb + csrc * 8;
      short* dst = ldsB + (wave * 4 + r) * 512;
      __builtin_amdgcn_global_load_lds((gas1_t)(const void*)src, (las3_t)(void*)dst, 16, 0, 0);
    }
    asm volatile("s_waitcnt vmcnt(0)" ::: "memory");
    __syncthreads();

    #pragma unroll
    for (int kk = 0; kk < 64; kk += 32){
      const int cc = (kk >> 3) + q;
      short8 af[4], bfr[4];
      #pragma unroll
      for (int mf = 0; mf < 4; ++mf){
        int row = wm * 64 + mf * 16 + ra;
        af[mf] = *(const short8*)(ldsA + row * 64 + ((cc ^ (row & 7)) << 3));
      }
      #pragma unroll
      for (int jf = 0; jf < 4; ++jf){
        int row = wn * 64 + jf * 16 + ra;
        bfr[jf] = *(const short8*)(ldsB + row * 64 + ((cc ^ (row & 7)) << 3));
      }
      #pragma unroll
      for (int mf = 0; mf < 4; ++mf)
        #pragma unroll
        for (int jf = 0; jf < 4; ++jf)
          acc[mf][jf] = __builtin_amdgcn_mfma_f32_16x16x32_bf16(af[mf], bfr[jf], acc[mf][jf], 0, 0, 0);
    }
    __syncthreads();
  }

  #pragma unroll
  for (int mf = 0; mf < 4; ++mf)
    #pragma unroll
    for (int jf = 0; jf < 4; ++jf)
      #pragma unroll
      for (int i = 0; i < 4; ++i){
        int row = m0 + wm * 64 + mf * 16 + q * 4 + i;
        int col = n0 + wn * 64 + jf * 16 + ra;
        xwx[(size_t)row * 4096 + col] = f2bf(acc[mf][jf][i]);
      }
}

// ---------------- persistent recurrence kernel, split-role waves ----------------
// flags layout (unsigned, 64B stride): flagsB = flags[bid*16] (all 256 blocks);
// flagsA = flags[4096 + bid*16] (blocks 0..127); goA = flags[6144]; goB = flags[6160].
// barB (h ready): consumers waves 0-3; aggregated by block255 wave0.
// barA (attn ready): consumers waves 4-7; aggregated by block255 wave4.
__global__ __launch_bounds__(512, 1) void k_loop(
    const short* __restrict__ W3T,
    const short* __restrict__ Abf,     // [128][1024][16] bf16
    short* __restrict__ hbuf,          // [65][128][1024] bf16 (rotating)
    short* __restrict__ abuf,          // [64][128][1024] bf16 (rotating)
    const float* __restrict__ cbuf,    // [128][1024] f32
    const short* __restrict__ xwx,     // [8192][4096] bf16
    const float* __restrict__ bias,    // [4096] f32
    float* __restrict__ out,           // [128][64][1024] f32
    unsigned* __restrict__ flags)
{
  __shared__ short Wl[65536];          // 128 KB weight slice, XOR-swizzled
  __shared__ float redu[4096];         // 16 KB reduce + fin union
  __shared__ float sred[4][16];

  unsigned* flagsB = flags;
  unsigned* flagsA = flags + 4096;
  unsigned* goA    = flags + 6144;
  unsigned* goB    = flags + 6160;

  const int tid  = threadIdx.x;
  const int lane = tid & 63;
  const int wave = tid >> 6;
  const int bid  = blockIdx.x;
  const int mh   = bid & 1;
  const int jb   = bid >> 1;
  const int u0   = jb * 8;
  const int ra   = lane & 15;
  const int q    = lane >> 4;
  const int mf2  = wave & 1;           // row half (32 rows)
  const int kh   = wave >> 1;          // K quarter (512); kh<2 reads h, kh>=2 reads abuf

  // ---- prologue: W slice -> LDS (once)
  #pragma unroll
  for (int it = 0; it < 16; ++it){
    int c16 = it * 512 + tid;
    int jl = c16 >> 8;
    int kc = c16 & 255;
    int jf = jl >> 4, rr = jl & 15;
    int j = (jf * 2 + (rr >> 3)) * 1024 + u0 + (rr & 7);
    short8 v = *(const short8*)(W3T + (size_t)j * 3072 + 1024 + kc * 8);
    int pc = (jf * 16 + rr) * 256 + (kc ^ (rr & 7));
    *(short8*)(Wl + pc * 8) = v;
  }

  // ---- hoisted attention A-fragments: waves 0-3, 4 h-positions per thread
  short8 af0[4], af1[4];               // af0[j] = A[bid][hh0+j][0:8], af1[j] = [8:16]
  const int hh0 = tid * 4;             // valid for tid<256
  if (wave < 4 && bid < 128){
    #pragma unroll
    for (int j = 0; j < 4; ++j){
      const short8* ap = (const short8*)(Abf + ((size_t)bid * 1024 + hh0 + j) * 16);
      af0[j] = ap[0]; af1[j] = ap[1];
    }
  }

  // ---- per-thread LSTM cell; c and bias in registers all steps
  const int n_loc = tid >> 3, uu = tid & 7;
  const int cn = mh * 64 + n_loc;
  const int cu = u0 + uu;
  float creg = cbuf[(size_t)cn * 1024 + cu];
  const float b0 = bias[cu], b1 = bias[1024 + cu], b2 = bias[2048 + cu], b3 = bias[3072 + cu];
  __syncthreads();

  for (int t = 0; t < 64; ++t){
    const short* hRp = hbuf + (size_t)t * 131072;        // slot t
    short*       hWp = hbuf + (size_t)(t + 1) * 131072;  // slot t+1
    short*       aT  = abuf + (size_t)t * 131072;

    // ---------- waves 0-3: wait h(t) ready (goB >= t), then attention ----------
    if (wave < 4){
      if (t > 0){
        if (bid == 255 && wave == 0){
          // aggregate flagsB (256, 4/lane) then publish goB = t
          for (;;){
            unsigned mn = 0xffffffffu;
            #pragma unroll
            for (int i = 0; i < 4; ++i){
              unsigned v = ld_llc_u32(&flagsB[(lane * 4 + i) * 16]);
              mn = v < mn ? v : mn;
            }
            if (__all(mn >= (unsigned)t)) break;
            __builtin_amdgcn_s_sleep(2);
          }
          if (lane == 0) st_llc_u32(goB, (unsigned)t);
        } else {
          if (lane == 0){
            while (ld_llc_u32(goB) < (unsigned)t) __builtin_amdgcn_s_sleep(1);
          }
        }
        asm volatile("" ::: "memory");
      }
      if (bid < 128){
        // scores: 4 h-positions per thread
        uint64_t hq = *(const uint64_t*)(hRp + bid * 1024 + hh0);   // 4 bf16, cached
        float hv[4];
        #pragma unroll
        for (int j = 0; j < 4; ++j) hv[j] = bf2f((short)((hq >> (16 * j)) & 0xffffu));
        float sc[16];
        #pragma unroll
        for (int l = 0; l < 8; ++l){
          float s0 = 0.f, s1 = 0.f;
          #pragma unroll
          for (int j = 0; j < 4; ++j){ s0 += hv[j] * bf2f(af0[j][l]); s1 += hv[j] * bf2f(af1[j][l]); }
          sc[l] = s0; sc[8 + l] = s1;
        }
        #pragma unroll
        for (int off = 1; off < 64; off <<= 1)
          #pragma unroll
          for (int l = 0; l < 16; ++l) sc[l] += __shfl_xor(sc[l], off);
        if (lane == 0)
          #pragma unroll
          for (int l = 0; l < 16; ++l) sred[wave][l] = sc[l];
      }
    }
    __syncthreads();                   // sync 1: sred ready

    if (wave < 4 && bid < 128){
      float s[16], mx = -1e30f, sum = 0.f;
      #pragma unroll
      for (int l = 0; l < 16; ++l){
        s[l] = (sred[0][l] + sred[1][l] + sred[2][l] + sred[3][l]) * 0.03125f;
        mx = fmaxf(mx, s[l]);
      }
      #pragma unroll
      for (int l = 0; l < 16; ++l){ s[l] = __expf(s[l] - mx); sum += s[l]; }
      const float inv = 1.f / sum;
      unsigned pk[2];
      #pragma unroll
      for (int jp = 0; jp < 2; ++jp){
        float a0 = 0.f, a1 = 0.f;
        #pragma unroll
        for (int l = 0; l < 8; ++l){
          a0 += s[l] * bf2f(af0[jp * 2][l])     + s[8 + l] * bf2f(af1[jp * 2][l]);
          a1 += s[l] * bf2f(af0[jp * 2 + 1][l]) + s[8 + l] * bf2f(af1[jp * 2 + 1][l]);
        }
        pk[jp] = (unsigned)(unsigned short)f2bf(a0 * inv)
               | ((unsigned)(unsigned short)f2bf(a1 * inv) << 16);
      }
      st_llc_u32(aT + bid * 1024 + hh0,     pk[0]);
      st_llc_u32(aT + bid * 1024 + hh0 + 2, pk[1]);
      asm volatile("s_waitcnt vmcnt(0)" ::: "memory");   // drain abuf stores (this wave)
    }
    __syncthreads();                   // sync 2: all attn stores drained
    if (tid == 0 && bid < 128) st_llc_u32(&flagsA[bid * 16], (unsigned)(t + 1));

    // ---------- xwx for this cell (constant data, cached) ----------
    const short* xp = xwx + ((size_t)cn * 64 + t) * 4096;
    const short xw0 = xp[cu], xw1 = xp[1024 + cu], xw2 = xp[2048 + cu], xw3 = xp[3072 + cu];

    auto loadA = [&](int ks, int m) -> short8 {
      const int kk = ks * 32 + q * 8;
      const int row = mh * 64 + mf2 * 32 + m * 16 + ra;
      const short* p = (kh < 2) ? (hRp + row * 1024 + kh * 512 + kk)
                                : (aT + row * 1024 + (kh - 2) * 512 + kk);
      return *(const short8*)p;
    };
    auto loadB = [&](int ks, int jf) -> short8 {
      const int kcg = kh * 64 + ks * 4 + q;
      const int sw = kcg ^ (ra & 7);
      return *(const short8*)(Wl + (((jf * 16 + ra) * 256) + sw) * 8);
    };

    short8 Ab[4][2], Bb[2][2];
    Bb[0][0] = loadB(0, 0); Bb[0][1] = loadB(0, 1);
    Bb[1][0] = loadB(1, 0); Bb[1][1] = loadB(1, 1);

    if (wave < 4){
      // h-half: no wait needed (h(t) visible since goB)
      #pragma unroll
      for (int p = 0; p < 4; ++p){ Ab[p][0] = loadA(p, 0); Ab[p][1] = loadA(p, 1); }
    } else {
      // abuf-half: wait attn ready (goA >= t+1); block255 wave4 aggregates
      if (bid == 255 && wave == 4){
        for (;;){
          unsigned mn = 0xffffffffu;
          unsigned v0 = ld_llc_u32(&flagsA[(lane * 2) * 16]);
          unsigned v1 = ld_llc_u32(&flagsA[(lane * 2 + 1) * 16]);
          mn = v0 < v1 ? v0 : v1;
          if (__all(mn >= (unsigned)(t + 1))) break;
          __builtin_amdgcn_s_sleep(2);
        }
        if (lane == 0) st_llc_u32(goA, (unsigned)(t + 1));
      } else {
        if (lane == 0){
          while (ld_llc_u32(goA) < (unsigned)(t + 1)) __builtin_amdgcn_s_sleep(1);
        }
      }
      asm volatile("" ::: "memory");
      #pragma unroll
      for (int p = 0; p < 4; ++p){ Ab[p][0] = loadA(p, 0); Ab[p][1] = loadA(p, 1); }
    }

    // ---------- GEMM: 16 K-iters, A 4-deep / B 2-deep ----------
    f32x4 acc[2][2];
    acc[0][0] = f32x4{0.f,0.f,0.f,0.f}; acc[0][1] = f32x4{0.f,0.f,0.f,0.f};
    acc[1][0] = f32x4{0.f,0.f,0.f,0.f}; acc[1][1] = f32x4{0.f,0.f,0.f,0.f};

    #pragma unroll
    for (int ks = 0; ks < 16; ++ks){
      short8 av0 = Ab[ks & 3][0], av1 = Ab[ks & 3][1];
      short8 bv0 = Bb[ks & 1][0], bv1 = Bb[ks & 1][1];
      if (ks < 12){ Ab[ks & 3][0] = loadA(ks + 4, 0); Ab[ks & 3][1] = loadA(ks + 4, 1); }
      if (ks < 14){ Bb[ks & 1][0] = loadB(ks + 2, 0); Bb[ks & 1][1] = loadB(ks + 2, 1); }
      acc[0][0] = __builtin_amdgcn_mfma_f32_16x16x32_bf16(av0, bv0, acc[0][0], 0, 0, 0);
      acc[0][1] = __builtin_amdgcn_mfma_f32_16x16x32_bf16(av0, bv1, acc[0][1], 0, 0, 0);
      acc[1][0] = __builtin_amdgcn_mfma_f32_16x16x32_bf16(av1, bv0, acc[1][0], 0, 0, 0);
      acc[1][1] = __builtin_amdgcn_mfma_f32_16x16x32_bf16(av1, bv1, acc[1][1], 0, 0, 0);
    }

    // ---------- reduction over kh (pairs) ----------
    auto ridx = [&](int m2, int khq, int m, int jf) -> float* {
      return &redu[((((m2 * 2 + khq) * 2 + m) * 2 + jf) * 64 + lane) * 4];
    };
    if (kh & 1){
      *(f32x4*)ridx(mf2, kh >> 1, 0, 0) = acc[0][0];
      *(f32x4*)ridx(mf2, kh >> 1, 0, 1) = acc[0][1];
      *(f32x4*)ridx(mf2, kh >> 1, 1, 0) = acc[1][0];
      *(f32x4*)ridx(mf2, kh >> 1, 1, 1) = acc[1][1];
    }
    __syncthreads();                   // sync 3
    if (!(kh & 1)){
      acc[0][0] += *(const f32x4*)ridx(mf2, kh >> 1, 0, 0);
      acc[0][1] += *(const f32x4*)ridx(mf2, kh >> 1, 0, 1);
      acc[1][0] += *(const f32x4*)ridx(mf2, kh >> 1, 1, 0);
      acc[1][1] += *(const f32x4*)ridx(mf2, kh >> 1, 1, 1);
    }
    __syncthreads();                   // sync 4
    if (kh == 2){
      *(f32x4*)ridx(mf2, 0, 0, 0) = acc[0][0];
      *(f32x4*)ridx(mf2, 0, 0, 1) = acc[0][1];
      *(f32x4*)ridx(mf2, 0, 1, 0) = acc[1][0];
      *(f32x4*)ridx(mf2, 0, 1, 1) = acc[1][1];
    }
    __syncthreads();                   // sync 5
    if (kh == 0){
      acc[0][0] += *(const f32x4*)ridx(mf2, 0, 0, 0);
      acc[0][1] += *(const f32x4*)ridx(mf2, 0, 0, 1);
      acc[1][0] += *(const f32x4*)ridx(mf2, 0, 1, 0);
      acc[1][1] += *(const f32x4*)ridx(mf2, 0, 1, 1);
    }
    __syncthreads();                   // sync 6
    if (kh == 0){
      #pragma unroll
      for (int m = 0; m < 2; ++m)
        #pragma unroll
        for (int jf = 0; jf < 2; ++jf){
          const int g = jf * 2 + (ra >> 3);
          const int nl = mf2 * 32 + m * 16 + q * 4;
          #pragma unroll
          for (int i = 0; i < 4; ++i)
            redu[g * 512 + (nl + i) * 8 + (ra & 7)] = acc[m][jf][i];
        }
    }
    __syncthreads();                   // sync 7

    // ---------- epilogue: 1 thread per (n,u) cell ----------
    float hn;
    {
      const float av = redu[tid]        + bf2f(xw0) + b0;
      const float fv = redu[512 + tid]  + bf2f(xw1) + b1;
      const float ov = redu[1024 + tid] + bf2f(xw2) + b2;
      const float gv = redu[1536 + tid] + bf2f(xw3) + b3;
      const float ig = 1.f / (1.f + __expf(-av));
      const float fg = 1.f / (1.f + __expf(-fv));
      const float og = 1.f / (1.f + __expf(-ov));
      const float gcl = fminf(fmaxf(gv, -20.f), 20.f);
      const float e2g = __expf(2.f * gcl);
      const float gg = (e2g - 1.f) / (e2g + 1.f);
      creg = fg * creg + ig * gg;
      const float ccl = fminf(fmaxf(creg, -20.f), 20.f);
      const float e2c = __expf(2.f * ccl);
      const float th = (e2c - 1.f) / (e2c + 1.f);
      hn = og * th;
      const float hn2 = __shfl_xor(hn, 1);
      if ((tid & 1) == 0){
        unsigned pk = (unsigned)(unsigned short)f2bf(hn)
                    | ((unsigned)(unsigned short)f2bf(hn2) << 16);
        st_llc_u32(hWp + (size_t)cn * 1024 + cu, pk);
      }
    }
    asm volatile("s_waitcnt vmcnt(0)" ::: "memory");     // drain h stores (per wave)
    __syncthreads();                   // sync 8: all h stores at LLC
    if (tid == 0 && t < 63) st_llc_u32(&flagsB[bid * 16], (unsigned)(t + 1));
    __builtin_nontemporal_store(hn, &out[((size_t)cn * 64 + t) * 1024 + cu]);
  }
}

// ---------------- launch ----------------

extern "C" void kernel_launch(void* const* d_in, const int* in_sizes, int n_in,
                              void* d_out, int out_size, void* d_ws, size_t ws_size,
                              hipStream_t stream)
{
  const float* x     = (const float*)d_in[0];
  const float* A     = (const float*)d_in[1];
  const float* Wx    = (const float*)d_in[2];
  const float* Wh    = (const float*)d_in[3];
  const float* Wattn = (const float*)d_in[4];
  const float* b     = (const float*)d_in[5];
  float* out = (float*)d_out;
  char* ws = (char*)d_ws;

  short*    W3T   = (short*)(ws + 0);             // 25165824
  short*    Abf   = (short*)(ws + 25165824);      //  4194304
  short*    xbf   = (short*)(ws + 29360128);      // 16777216
  short*    xwx   = (short*)(ws + 46137344);      // 67108864 (bf16)
  short*    hbuf  = (short*)(ws + 113246208);     // 65 slots x 262144 = 17039360
  short*    abuf  = (short*)(ws + 130285568);     // 64 slots x 262144 = 16777216
  float*    cbuf  = (float*)(ws + 147062784);     //   524288
  unsigned* flags = (unsigned*)(ws + 147587072);  //    32768

  hipLaunchKernelGGL(k_wt,   dim3(48 * 64), dim3(256), 0, stream, Wx, Wh, Wattn, W3T);
  hipLaunchKernelGGL(k_cast, dim3(2097152 / 256), dim3(256), 0, stream, x, xbf, 2097152);
  hipLaunchKernelGGL(k_cast, dim3(524288 / 256),  dim3(256), 0, stream, A, Abf, 524288);
  hipLaunchKernelGGL(k_init, dim3(512), dim3(256), 0, stream, A, cbuf, hbuf, flags);
  hipLaunchKernelGGL(k_xwx,  dim3(2048), dim3(256), 0, stream, xbf, W3T, xwx);
  hipLaunchKernelGGL(k_loop, dim3(256), dim3(512), 0, stream,
                     W3T, Abf, hbuf, abuf, cbuf, xwx, b, out, flags);
}

// Round 11
// 892.804 us; speedup vs baseline: 4.8818x; 1.0489x over previous
//
#include <hip/hip_runtime.h>
#include <stdint.h>
#include <math.h>

typedef __attribute__((ext_vector_type(8))) short short8;
typedef __attribute__((ext_vector_type(4))) short short4v;
typedef __attribute__((ext_vector_type(4))) float f32x4;

__device__ __forceinline__ short f2bf(float f){
  union { float f; uint32_t u; } x; x.f = f;
  uint32_t r = x.u + 0x7fffu + ((x.u >> 16) & 1u);
  return (short)(r >> 16);
}
__device__ __forceinline__ float bf2f(short s){
  union { uint32_t u; float f; } x; x.u = ((uint32_t)(uint16_t)s) << 16;
  return x.f;
}

__device__ __forceinline__ unsigned ld_llc_u32(const void* p){
  return __hip_atomic_load((const unsigned*)p, __ATOMIC_RELAXED, __HIP_MEMORY_SCOPE_AGENT);
}
__device__ __forceinline__ void st_llc_u32(void* p, unsigned v){
  __hip_atomic_store((unsigned*)p, v, __ATOMIC_RELAXED, __HIP_MEMORY_SCOPE_AGENT);
}

// ---------------- prep kernels ----------------

__global__ __launch_bounds__(256) void k_wt(const float* __restrict__ Wx,
                                            const float* __restrict__ Wh,
                                            const float* __restrict__ Wattn,
                                            short* __restrict__ W3T){
  __shared__ float tile[64][65];
  int bk = blockIdx.x % 48, bj = blockIdx.x / 48;
  int tx = threadIdx.x & 63, ty = threadIdx.x >> 6;
  int k0 = bk * 64, j0 = bj * 64;
  #pragma unroll
  for (int i = 0; i < 16; ++i){
    int kk = ty * 16 + i;
    int k = k0 + kk;
    const float* src = (k < 1024) ? (Wx + (size_t)k * 4096)
                     : (k < 2048) ? (Wh + (size_t)(k - 1024) * 4096)
                                  : (Wattn + (size_t)(k - 2048) * 4096);
    tile[kk][tx] = src[j0 + tx];
  }
  __syncthreads();
  #pragma unroll
  for (int i = 0; i < 16; ++i){
    int jj = ty * 16 + i;
    W3T[(size_t)(j0 + jj) * 3072 + k0 + tx] = f2bf(tile[tx][jj]);
  }
}

__global__ __launch_bounds__(256) void k_cast(const float* __restrict__ in,
                                              short* __restrict__ out, int n4){
  int i = blockIdx.x * 256 + threadIdx.x;
  if (i >= n4) return;
  float4 v = ((const float4*)in)[i];
  short4v o; o[0] = f2bf(v.x); o[1] = f2bf(v.y); o[2] = f2bf(v.z); o[3] = f2bf(v.w);
  *(short4v*)(out + (size_t)i * 4) = o;
}

// cast A -> Abf [n][h][16] and transposed Atr [n][16][1024]
__global__ __launch_bounds__(256) void k_castA(const float* __restrict__ A,
                                               short* __restrict__ Abf,
                                               short* __restrict__ Atr){
  const int n = blockIdx.x;
  const int tid = threadIdx.x;
  __shared__ short tile[256][17];
  for (int it = 0; it < 4; ++it){
    int h = it * 256 + tid;
    const float* src = A + ((size_t)n * 1024 + h) * 16;
    short o[16];
    #pragma unroll
    for (int l = 0; l < 16; ++l) o[l] = f2bf(src[l]);
    short8 p0, p1;
    #pragma unroll
    for (int l = 0; l < 8; ++l){ p0[l] = o[l]; p1[l] = o[8 + l]; }
    short8* dst = (short8*)(Abf + ((size_t)n * 1024 + h) * 16);
    dst[0] = p0; dst[1] = p1;
    #pragma unroll
    for (int l = 0; l < 16; ++l) tile[tid][l] = o[l];
    __syncthreads();
    {
      int l = tid >> 4, hc = (tid & 15) * 16;
      short tmp[16];
      #pragma unroll
      for (int k = 0; k < 16; ++k) tmp[k] = tile[hc + k][l];
      short8 q0, q1;
      #pragma unroll
      for (int k = 0; k < 8; ++k){ q0[k] = tmp[k]; q1[k] = tmp[8 + k]; }
      short8* d2 = (short8*)(Atr + (size_t)n * 16384 + l * 1024 + it * 256 + hc);
      d2[0] = q0; d2[1] = q1;
    }
    __syncthreads();
  }
}

// h0 = c0 = mean over L=16 of A; zero flags (h-flags + w-tags)
__global__ __launch_bounds__(256) void k_init(const float* __restrict__ A,
                                              float* __restrict__ c,
                                              short* __restrict__ hb0,
                                              unsigned* __restrict__ flags){
  int idx = blockIdx.x * 256 + threadIdx.x;
  if (idx < 8192) flags[idx] = 0u;
  const float* p = A + (size_t)idx * 16;
  float s = 0.f;
  #pragma unroll
  for (int l = 0; l < 16; ++l) s += p[l];
  s *= (1.f / 16.f);
  c[idx] = s;
  hb0[idx] = f2bf(s);
}

typedef const __attribute__((address_space(1))) uint32_t* gas1_t;
typedef __attribute__((address_space(3))) uint32_t* las3_t;

// xwx = x @ Wx  (bf16 out), 128x128 tile GEMM
__global__ __launch_bounds__(256) void k_xwx(const short* __restrict__ xbf,
                                             const short* __restrict__ W3T,
                                             short* __restrict__ xwx){
  __shared__ short ldsA[128 * 64];
  __shared__ short ldsB[128 * 64];
  const int tid  = threadIdx.x;
  const int lane = tid & 63;
  const int wave = tid >> 6;
  const int orig = blockIdx.x;
  const int wg = (orig & 7) * 256 + (orig >> 3);
  const int n_t = wg >> 6;
  const int m_t = wg & 63;
  const int m0 = m_t * 128;
  const int n0 = n_t * 128;
  const int ra = lane & 15;
  const int q  = lane >> 4;

  f32x4 acc[4][4];
  #pragma unroll
  for (int mf = 0; mf < 4; ++mf)
    #pragma unroll
    for (int jf = 0; jf < 4; ++jf) acc[mf][jf] = f32x4{0.f,0.f,0.f,0.f};

  const int wm = wave >> 1;
  const int wn = wave & 1;

  for (int kt = 0; kt < 16; ++kt){
    const int kb = kt * 64;
    #pragma unroll
    for (int r = 0; r < 4; ++r){
      int id = (wave * 4 + r) * 64 + lane;
      int row = id >> 3, c = id & 7;
      int csrc = c ^ (row & 7);
      const short* src = xbf + (size_t)(m0 + row) * 1024 + kb + csrc * 8;
      short* dst = ldsA + (wave * 4 + r) * 512;
      __builtin_amdgcn_global_load_lds((gas1_t)(const void*)src, (las3_t)(void*)dst, 16, 0, 0);
    }
    #pragma unroll
    for (int r = 0; r < 4; ++r){
      int id = (wave * 4 + r) * 64 + lane;
      int row = id >> 3, c = id & 7;
      int csrc = c ^ (row & 7);
      const short* src = W3T + (size_t)(n0 + row) * 3072 + kb + csrc * 8;
      short* dst = ldsB + (wave * 4 + r) * 512;
      __builtin_amdgcn_global_load_lds((gas1_t)(const void*)src, (las3_t)(void*)dst, 16, 0, 0);
    }
    asm volatile("s_waitcnt vmcnt(0)" ::: "memory");
    __syncthreads();

    #pragma unroll
    for (int kk = 0; kk < 64; kk += 32){
      const int cc = (kk >> 3) + q;
      short8 af[4], bfr[4];
      #pragma unroll
      for (int mf = 0; mf < 4; ++mf){
        int row = wm * 64 + mf * 16 + ra;
        af[mf] = *(const short8*)(ldsA + row * 64 + ((cc ^ (row & 7)) << 3));
      }
      #pragma unroll
      for (int jf = 0; jf < 4; ++jf){
        int row = wn * 64 + jf * 16 + ra;
        bfr[jf] = *(const short8*)(ldsB + row * 64 + ((cc ^ (row & 7)) << 3));
      }
      #pragma unroll
      for (int mf = 0; mf < 4; ++mf)
        #pragma unroll
        for (int jf = 0; jf < 4; ++jf)
          acc[mf][jf] = __builtin_amdgcn_mfma_f32_16x16x32_bf16(af[mf], bfr[jf], acc[mf][jf], 0, 0, 0);
    }
    __syncthreads();
  }

  #pragma unroll
  for (int mf = 0; mf < 4; ++mf)
    #pragma unroll
    for (int jf = 0; jf < 4; ++jf)
      #pragma unroll
      for (int i = 0; i < 4; ++i){
        int row = m0 + wm * 64 + mf * 16 + q * 4 + i;
        int col = n0 + wn * 64 + jf * 16 + ra;
        xwx[(size_t)row * 4096 + col] = f2bf(acc[mf][jf][i]);
      }
}

// P[n][j][l] = sum_h Wattn[h][j] * A[n][h][l]   (j-major, l contiguous)
// A-frag rows = j from W3T[j][2048+h]; B-frag rows = l from Atr[n][l][h].
__global__ __launch_bounds__(256) void k_pw(const short* __restrict__ W3T,
                                            const short* __restrict__ Atr,
                                            short* __restrict__ P){
  const int tid  = threadIdx.x;
  const int lane = tid & 63;
  const int wave = tid >> 6;
  const int blk  = blockIdx.x;        // 2048
  const int n    = blk >> 4;
  const int jblk = blk & 15;
  const int j0   = jblk * 256 + wave * 64;
  const int ra = lane & 15;
  const int q  = lane >> 4;

  f32x4 acc[4];
  #pragma unroll
  for (int mf = 0; mf < 4; ++mf) acc[mf] = f32x4{0.f,0.f,0.f,0.f};

  auto loadA = [&](int ks, int mf) -> short8 {
    return *(const short8*)(W3T + (size_t)(j0 + mf*16 + ra) * 3072 + 2048 + ks * 32 + q * 8);
  };
  auto loadB = [&](int ks) -> short8 {
    return *(const short8*)(Atr + (size_t)n * 16384 + ra * 1024 + ks * 32 + q * 8);
  };

  short8 aC[4], bC, aN[4], bN;
  #pragma unroll
  for (int mf = 0; mf < 4; ++mf) aC[mf] = loadA(0, mf);
  bC = loadB(0);
  for (int ks = 0; ks < 32; ++ks){
    bool more = (ks + 1) < 32;
    if (more){
      #pragma unroll
      for (int mf = 0; mf < 4; ++mf) aN[mf] = loadA(ks + 1, mf);
      bN = loadB(ks + 1);
    }
    #pragma unroll
    for (int mf = 0; mf < 4; ++mf)
      acc[mf] = __builtin_amdgcn_mfma_f32_16x16x32_bf16(aC[mf], bC, acc[mf], 0, 0, 0);
    if (more){
      #pragma unroll
      for (int mf = 0; mf < 4; ++mf) aC[mf] = aN[mf];
      bC = bN;
    }
  }
  #pragma unroll
  for (int mf = 0; mf < 4; ++mf)
    #pragma unroll
    for (int i = 0; i < 4; ++i){
      int j = j0 + mf * 16 + q * 4 + i;
      P[(size_t)(n * 4096 + j) * 16 + ra] = f2bf(acc[mf][i]);
    }
}

// ---------------- persistent recurrence kernel ----------------
// 256 blocks x 512 threads. Block: mh = bid&1, jb = bid>>1, u0 = jb*8.
// Wh slice [32j][1024k] in LDS (64 KB). 8 waves = (mf2 = wave&1) x (kh = wave>>1,
// 256k each). Score blocks (bid<128) handle n_s = mh*64 + jb on waves 0-3; only
// the 16 softmax weights w cross blocks (128B line + LLC tag per n).
// Leaderless: all waves poll the 128 h-flags of their own half directly.
__global__ __launch_bounds__(512, 1) void k_loop(
    const short* __restrict__ W3T,
    const short* __restrict__ Abf,     // [128][1024][16] bf16
    const short* __restrict__ P,       // [128][4096][16] bf16
    short* __restrict__ hbuf,          // [65][128][1024] bf16 (rotating)
    float* __restrict__ wbuf,          // [64][128][32] f32 (rotating, 128B/n)
    const float* __restrict__ cbuf,    // [128][1024] f32
    const short* __restrict__ xwx,     // [8192][4096] bf16
    const float* __restrict__ bias,    // [4096] f32
    float* __restrict__ out,           // [128][64][1024] f32
    unsigned* __restrict__ flags)
{
  __shared__ short Wl[32768];          // 64 KB Wh slice, XOR-swizzled
  __shared__ float redu[4096];         // 16 KB reduce + fin union
  __shared__ float sred[4][16];
  __shared__ float wlds[64][16];       // w for this block's 64 n

  unsigned* flagsB = flags;            // [(mh*128 + jb)*16]
  unsigned* wtag   = flags + 4096;     // [n*16]

  const int tid  = threadIdx.x;
  const int lane = tid & 63;
  const int wave = tid >> 6;
  const int bid  = blockIdx.x;
  const int mh   = bid & 1;
  const int jb   = bid >> 1;
  const int u0   = jb * 8;
  const int ra   = lane & 15;
  const int q    = lane >> 4;
  const int mf2  = wave & 1;
  const int kh   = wave >> 1;          // 0..3, 256 k each
  const bool isScore = (bid < 128);
  const int n_s  = mh * 64 + jb;       // score-n (jb<64 when bid<128)

  // ---- prologue: Wh slice -> LDS (once): 32j x 1024k
  #pragma unroll
  for (int it = 0; it < 8; ++it){
    int c16 = it * 512 + tid;          // 0..4095
    int jl = c16 >> 7;                 // 0..31
    int kc = c16 & 127;
    int jf = jl >> 4, rr = jl & 15;
    int j = (jf * 2 + (rr >> 3)) * 1024 + u0 + (rr & 7);
    short8 v = *(const short8*)(W3T + (size_t)j * 3072 + 1024 + kc * 8);
    int pc = (jf * 16 + rr) * 128 + (kc ^ (rr & 7));
    *(short8*)(Wl + pc * 8) = v;
  }

  // ---- hoisted attention A-fragments (step-invariant), waves 0-3 of score blocks
  short8 af0[4], af1[4];
  const int hh0 = tid * 4;             // tid<256
  if (wave < 4 && isScore){
    #pragma unroll
    for (int j = 0; j < 4; ++j){
      const short8* ap = (const short8*)(Abf + ((size_t)n_s * 1024 + hh0 + j) * 16);
      af0[j] = ap[0]; af1[j] = ap[1];
    }
  }

  // ---- per-thread LSTM cell
  const int n_loc = tid >> 3, uu = tid & 7;
  const int cn = mh * 64 + n_loc;
  const int cu = u0 + uu;
  float creg = cbuf[(size_t)cn * 1024 + cu];
  const float b0 = bias[cu], b1 = bias[1024 + cu], b2 = bias[2048 + cu], b3 = bias[3072 + cu];
  __syncthreads();

  for (int t = 0; t < 64; ++t){
    const short* hRp = hbuf + (size_t)t * 131072;
    short*       hWp = hbuf + (size_t)(t + 1) * 131072;
    float*       wT  = wbuf + (size_t)t * 4096;   // slot t, [128 n][32 f32]

    // ---------- all waves: direct-poll h(t) flags of own half ----------
    if (t > 0){
      const unsigned tgt = (unsigned)t;
      for (;;){
        unsigned v0 = ld_llc_u32(&flagsB[(mh * 128 + lane * 2)     * 16]);
        unsigned v1 = ld_llc_u32(&flagsB[(mh * 128 + lane * 2 + 1) * 16]);
        unsigned mn = v0 < v1 ? v0 : v1;
        if (__all(mn >= tgt)) break;
        __builtin_amdgcn_s_sleep(1);
      }
    }

    // ---------- scores (score blocks, waves 0-3) ----------
    if (wave < 4 && isScore){
      uint64_t hq = *(const uint64_t*)(hRp + n_s * 1024 + hh0);   // cached
      float hv[4];
      #pragma unroll
      for (int j = 0; j < 4; ++j) hv[j] = bf2f((short)((hq >> (16 * j)) & 0xffffu));
      float sc[16];
      #pragma unroll
      for (int l = 0; l < 8; ++l){
        float s0 = 0.f, s1 = 0.f;
        #pragma unroll
        for (int j = 0; j < 4; ++j){ s0 += hv[j] * bf2f(af0[j][l]); s1 += hv[j] * bf2f(af1[j][l]); }
        sc[l] = s0; sc[8 + l] = s1;
      }
      #pragma unroll
      for (int off = 1; off < 64; off <<= 1)
        #pragma unroll
        for (int l = 0; l < 16; ++l) sc[l] += __shfl_xor(sc[l], off);
      if (lane == 0)
        #pragma unroll
        for (int l = 0; l < 16; ++l) sred[wave][l] = sc[l];
    }
    __syncthreads();                   // sync1: sred ready

    // ---------- wave 0 of score blocks: softmax -> publish w + tag ----------
    if (wave == 0 && isScore){
      float s[16], mx = -1e30f, sum = 0.f;
      #pragma unroll
      for (int l = 0; l < 16; ++l){
        s[l] = (sred[0][l] + sred[1][l] + sred[2][l] + sred[3][l]) * 0.03125f;
        mx = fmaxf(mx, s[l]);
      }
      #pragma unroll
      for (int l = 0; l < 16; ++l){ s[l] = __expf(s[l] - mx); sum += s[l]; }
      const float inv = 1.f / sum;
      #pragma unroll
      for (int l = 0; l < 16; ++l){
        if (lane == l){
          union { float f; unsigned u; } cv; cv.f = s[l] * inv;
          st_llc_u32(&wT[n_s * 32 + l], cv.u);
        }
      }
      asm volatile("s_waitcnt vmcnt(0)" ::: "memory");
      if (lane == 0) st_llc_u32(&wtag[n_s * 16], (unsigned)(t + 1));
    }

    // ---------- xwx for this cell (constant, cached) ----------
    const short* xp = xwx + ((size_t)cn * 64 + t) * 4096;
    const short xw0 = xp[cu], xw1 = xp[1024 + cu], xw2 = xp[2048 + cu], xw3 = xp[3072 + cu];

    // ---------- GEMM h@Wh: wave slice k = kh*256..+256, 8 ks iters ----------
    auto loadA = [&](int ks, int m) -> short8 {
      const int kk = kh * 256 + ks * 32 + q * 8;
      const int row = mh * 64 + mf2 * 32 + m * 16 + ra;
      return *(const short8*)(hRp + row * 1024 + kk);
    };
    auto loadB = [&](int ks, int jf) -> short8 {
      const int kcg = kh * 32 + ks * 4 + q;
      const int sw = kcg ^ (ra & 7);
      return *(const short8*)(Wl + (((jf * 16 + ra) * 128) + sw) * 8);
    };

    short8 Ab[4][2], Bb[2][2];
    Bb[0][0] = loadB(0, 0); Bb[0][1] = loadB(0, 1);
    Bb[1][0] = loadB(1, 0); Bb[1][1] = loadB(1, 1);
    #pragma unroll
    for (int p = 0; p < 4; ++p){ Ab[p][0] = loadA(p, 0); Ab[p][1] = loadA(p, 1); }

    f32x4 acc[2][2];
    acc[0][0] = f32x4{0.f,0.f,0.f,0.f}; acc[0][1] = f32x4{0.f,0.f,0.f,0.f};
    acc[1][0] = f32x4{0.f,0.f,0.f,0.f}; acc[1][1] = f32x4{0.f,0.f,0.f,0.f};

    #pragma unroll
    for (int ks = 0; ks < 8; ++ks){
      short8 av0 = Ab[ks & 3][0], av1 = Ab[ks & 3][1];
      short8 bv0 = Bb[ks & 1][0], bv1 = Bb[ks & 1][1];
      if (ks < 4){ Ab[ks & 3][0] = loadA(ks + 4, 0); Ab[ks & 3][1] = loadA(ks + 4, 1); }
      if (ks < 6){ Bb[ks & 1][0] = loadB(ks + 2, 0); Bb[ks & 1][1] = loadB(ks + 2, 1); }
      acc[0][0] = __builtin_amdgcn_mfma_f32_16x16x32_bf16(av0, bv0, acc[0][0], 0, 0, 0);
      acc[0][1] = __builtin_amdgcn_mfma_f32_16x16x32_bf16(av0, bv1, acc[0][1], 0, 0, 0);
      acc[1][0] = __builtin_amdgcn_mfma_f32_16x16x32_bf16(av1, bv0, acc[1][0], 0, 0, 0);
      acc[1][1] = __builtin_amdgcn_mfma_f32_16x16x32_bf16(av1, bv1, acc[1][1], 0, 0, 0);
    }

    // ---------- reduction over kh (pairs), R10 structure ----------
    auto ridx = [&](int m2, int khq, int m, int jf) -> float* {
      return &redu[((((m2 * 2 + khq) * 2 + m) * 2 + jf) * 64 + lane) * 4];
    };
    if (kh & 1){
      *(f32x4*)ridx(mf2, kh >> 1, 0, 0) = acc[0][0];
      *(f32x4*)ridx(mf2, kh >> 1, 0, 1) = acc[0][1];
      *(f32x4*)ridx(mf2, kh >> 1, 1, 0) = acc[1][0];
      *(f32x4*)ridx(mf2, kh >> 1, 1, 1) = acc[1][1];
    }
    __syncthreads();                   // sync3
    if (!(kh & 1)){
      acc[0][0] += *(const f32x4*)ridx(mf2, kh >> 1, 0, 0);
      acc[0][1] += *(const f32x4*)ridx(mf2, kh >> 1, 0, 1);
      acc[1][0] += *(const f32x4*)ridx(mf2, kh >> 1, 1, 0);
      acc[1][1] += *(const f32x4*)ridx(mf2, kh >> 1, 1, 1);
    }
    // wave2 (S1-writer, otherwise idle): poll w-tags + load w -> wlds
    if (wave == 2){
      const unsigned tgt = (unsigned)(t + 1);
      for (;;){
        unsigned v = ld_llc_u32(&wtag[(mh * 64 + lane) * 16]);
        if (__all(v >= tgt)) break;
        __builtin_amdgcn_s_sleep(1);
      }
      const f32x4* wp = (const f32x4*)(wT + (mh * 64 + lane) * 32);   // cached, fresh line
      f32x4 w0 = wp[0], w1 = wp[1], w2 = wp[2], w3 = wp[3];
      f32x4* wd = (f32x4*)&wlds[lane][0];
      wd[0] = w0; wd[1] = w1; wd[2] = w2; wd[3] = w3;
    }
    __syncthreads();                   // sync4
    if (kh == 2){
      *(f32x4*)ridx(mf2, 0, 0, 0) = acc[0][0];
      *(f32x4*)ridx(mf2, 0, 0, 1) = acc[0][1];
      *(f32x4*)ridx(mf2, 0, 1, 0) = acc[1][0];
      *(f32x4*)ridx(mf2, 0, 1, 1) = acc[1][1];
    }
    __syncthreads();                   // sync5
    if (kh == 0){
      acc[0][0] += *(const f32x4*)ridx(mf2, 0, 0, 0);
      acc[0][1] += *(const f32x4*)ridx(mf2, 0, 0, 1);
      acc[1][0] += *(const f32x4*)ridx(mf2, 0, 1, 0);
      acc[1][1] += *(const f32x4*)ridx(mf2, 0, 1, 1);
    }
    __syncthreads();                   // sync6
    if (kh == 0){
      #pragma unroll
      for (int m = 0; m < 2; ++m)
        #pragma unroll
        for (int jf = 0; jf < 2; ++jf){
          const int g = jf * 2 + (ra >> 3);
          const int nl = mf2 * 32 + m * 16 + q * 4;
          #pragma unroll
          for (int i = 0; i < 4; ++i)
            redu[g * 512 + (nl + i) * 8 + (ra & 7)] = acc[m][jf][i];
        }
    }
    __syncthreads();                   // sync7

    // ---------- epilogue: 1 thread per (n,u) cell ----------
    float hn;
    {
      float wl[16];
      #pragma unroll
      for (int l = 0; l < 16; ++l) wl[l] = wlds[n_loc][l];
      float pg[4];
      #pragma unroll
      for (int g = 0; g < 4; ++g){
        const short8* pp = (const short8*)(P + ((size_t)cn * 4096 + g * 1024 + cu) * 16);
        short8 pa = pp[0], pb = pp[1];
        float s = 0.f;
        #pragma unroll
        for (int l = 0; l < 8; ++l){ s += bf2f(pa[l]) * wl[l]; s += bf2f(pb[l]) * wl[8 + l]; }
        pg[g] = s;
      }
      const float av = redu[tid]        + bf2f(xw0) + pg[0] + b0;
      const float fv = redu[512 + tid]  + bf2f(xw1) + pg[1] + b1;
      const float ov = redu[1024 + tid] + bf2f(xw2) + pg[2] + b2;
      const float gv = redu[1536 + tid] + bf2f(xw3) + pg[3] + b3;
      const float ig = 1.f / (1.f + __expf(-av));
      const float fg = 1.f / (1.f + __expf(-fv));
      const float og = 1.f / (1.f + __expf(-ov));
      const float gcl = fminf(fmaxf(gv, -20.f), 20.f);
      const float e2g = __expf(2.f * gcl);
      const float gg = (e2g - 1.f) / (e2g + 1.f);
      creg = fg * creg + ig * gg;
      const float ccl = fminf(fmaxf(creg, -20.f), 20.f);
      const float e2c = __expf(2.f * ccl);
      const float th = (e2c - 1.f) / (e2c + 1.f);
      hn = og * th;
      const float hn2 = __shfl_xor(hn, 1);
      if ((tid & 1) == 0){
        unsigned pk = (unsigned)(unsigned short)f2bf(hn)
                    | ((unsigned)(unsigned short)f2bf(hn2) << 16);
        st_llc_u32(hWp + (size_t)cn * 1024 + cu, pk);
      }
    }
    asm volatile("s_waitcnt vmcnt(0)" ::: "memory");   // drain h stores (per wave)
    __syncthreads();                   // sync8
    if (tid == 0 && t < 63) st_llc_u32(&flagsB[(mh * 128 + jb) * 16], (unsigned)(t + 1));
    __builtin_nontemporal_store(hn, &out[((size_t)cn * 64 + t) * 1024 + cu]);
  }
}

// ---------------- launch ----------------

extern "C" void kernel_launch(void* const* d_in, const int* in_sizes, int n_in,
                              void* d_out, int out_size, void* d_ws, size_t ws_size,
                              hipStream_t stream)
{
  const float* x     = (const float*)d_in[0];
  const float* A     = (const float*)d_in[1];
  const float* Wx    = (const float*)d_in[2];
  const float* Wh    = (const float*)d_in[3];
  const float* Wattn = (const float*)d_in[4];
  const float* b     = (const float*)d_in[5];
  float* out = (float*)d_out;
  char* ws = (char*)d_ws;

  short*    W3T   = (short*)(ws + 0);             // 25165824
  short*    Abf   = (short*)(ws + 25165824);      //  4194304
  short*    Atr   = (short*)(ws + 29360128);      //  4194304
  short*    xbf   = (short*)(ws + 33554432);      // 16777216
  short*    xwx   = (short*)(ws + 50331648);      // 67108864
  short*    P     = (short*)(ws + 117440512);     // 16777216
  short*    hbuf  = (short*)(ws + 134217728);     // 65 x 262144 = 17039360
  float*    wbuf  = (float*)(ws + 151257088);     // 64 x 16384 = 1048576
  float*    cbuf  = (float*)(ws + 152305664);     //   524288
  unsigned* flags = (unsigned*)(ws + 152829952);  //    32768

  hipLaunchKernelGGL(k_wt,    dim3(48 * 64), dim3(256), 0, stream, Wx, Wh, Wattn, W3T);
  hipLaunchKernelGGL(k_cast,  dim3(2097152 / 256), dim3(256), 0, stream, x, xbf, 2097152);
  hipLaunchKernelGGL(k_castA, dim3(128), dim3(256), 0, stream, A, Abf, Atr);
  hipLaunchKernelGGL(k_init,  dim3(512), dim3(256), 0, stream, A, cbuf, hbuf, flags);
  hipLaunchKernelGGL(k_xwx,   dim3(2048), dim3(256), 0, stream, xbf, W3T, xwx);
  hipLaunchKernelGGL(k_pw,    dim3(2048), dim3(256), 0, stream, W3T, Atr, P);
  hipLaunchKernelGGL(k_loop,  dim3(256), dim3(512), 0, stream,
                     W3T, Abf, P, hbuf, wbuf, cbuf, xwx, b, out, flags);
}